// Round 1
// baseline (575.594 us; speedup 1.0000x reference)
//
#include <hip/hip_runtime.h>
#include <hip/hip_bf16.h>
#include <math.h>

// Problem constants
#define B_ 2
#define L_ 1000
#define D_ 288
#define H_ 8
#define DIM_ 36
#define DFF_ 576
#define KS_ 250
#define NQ_ 250
#define BH_ (B_ * H_)
#define EPS_ 1e-5f

__device__ __forceinline__ float gelu_exact(float x) {
    return 0.5f * x * (1.0f + erff(x * 0.70710678118654752f));
}

// ---------------------------------------------------------------------------
// K1: QKV projection.  x[b,l,:] @ W{q,k,v}.T + b  ->  Q/K/V in [bh, l, dim]
// 8 rows per block so each weight row streamed from L2 is reused 8x.
// grid 250, block 256
// ---------------------------------------------------------------------------
__global__ __launch_bounds__(256) void qkv_kernel(
    const float* __restrict__ x,
    const float* __restrict__ Wq, const float* __restrict__ bq,
    const float* __restrict__ Wk, const float* __restrict__ bk,
    const float* __restrict__ Wv, const float* __restrict__ bv,
    float* __restrict__ Q, float* __restrict__ K, float* __restrict__ V)
{
    constexpr int R = 8;
    __shared__ float xs[R][D_];
    const int base = blockIdx.x * R;   // base row in [0, 2000)
    const int tid = threadIdx.x;

    for (int idx = tid; idx < R * D_; idx += 256) {
        int r = idx / D_, j = idx % D_;
        xs[r][j] = x[(base + r) * D_ + j];
    }
    __syncthreads();

    const float* Ws[3] = {Wq, Wk, Wv};
    const float* Bs[3] = {bq, bk, bv};
    float* Os[3] = {Q, K, V};

    for (int j = tid; j < 3 * D_; j += 256) {
        int which = j / D_, jj = j % D_;
        const float* wrow = Ws[which] + jj * D_;
        float bias = Bs[which][jj];
        float acc[R];
#pragma unroll
        for (int r = 0; r < R; r++) acc[r] = bias;
        for (int d = 0; d < D_; d++) {
            float wv = wrow[d];
#pragma unroll
            for (int r = 0; r < R; r++) acc[r] += xs[r][d] * wv;
        }
        int h = jj / DIM_, dd = jj % DIM_;
        float* o = Os[which];
#pragma unroll
        for (int r = 0; r < R; r++) {
            int row = base + r;
            int b = row / L_, l = row % L_;
            o[((b * H_ + h) * L_ + l) * DIM_ + dd] = acc[r];
        }
    }
}

// ---------------------------------------------------------------------------
// K2: Vmean[bh, d] = mean over l of V[bh, l, d].   576 outputs.
// ---------------------------------------------------------------------------
__global__ __launch_bounds__(256) void vmean_kernel(
    const float* __restrict__ V, float* __restrict__ Vmean)
{
    int idx = blockIdx.x * blockDim.x + threadIdx.x;
    if (idx >= BH_ * DIM_) return;
    int bh = idx / DIM_, d = idx % DIM_;
    const float* base = V + (size_t)bh * L_ * DIM_ + d;
    float s = 0.f;
    for (int l = 0; l < L_; l++) s += base[l * DIM_];
    Vmean[idx] = s * (1.0f / L_);
}

// ---------------------------------------------------------------------------
// K3: sparsity measure.  One wave per (bh, l): 250 sampled key dots.
// measure = max(scores) - sum(scores)/L
// grid 4000, block 256 (4 waves)
// ---------------------------------------------------------------------------
__global__ __launch_bounds__(256) void measure_kernel(
    const float* __restrict__ Q, const float* __restrict__ K,
    const int* __restrict__ index_key, float* __restrict__ measure)
{
    const int w = threadIdx.x >> 6;
    const int lane = threadIdx.x & 63;
    const int wid = blockIdx.x * 4 + w;      // 0..15999
    const int bh = wid / L_;
    const int l = wid % L_;

    __shared__ float qs[4][DIM_];
    if (lane < DIM_) qs[w][lane] = Q[(bh * L_ + l) * DIM_ + lane];
    __syncthreads();

    const int* ik = index_key + l * KS_;
    const float* Kb = K + (size_t)bh * L_ * DIM_;

    float mx = -1e30f, sm = 0.f;
    for (int s = lane; s < KS_; s += 64) {
        int kidx = ik[s];
        const float* kr = Kb + kidx * DIM_;
        float acc = 0.f;
#pragma unroll
        for (int d = 0; d < DIM_; d++) acc += qs[w][d] * kr[d];
        mx = fmaxf(mx, acc);
        sm += acc;
    }
#pragma unroll
    for (int off = 32; off; off >>= 1) {
        mx = fmaxf(mx, __shfl_xor(mx, off));
        sm += __shfl_xor(sm, off);
    }
    if (lane == 0) measure[wid] = mx - sm * (1.0f / (float)L_);
}

// ---------------------------------------------------------------------------
// K4: top-NQ selection per (b,h) via O(N^2) rank counting in LDS.
// Deterministic tie-break (lower index wins). grid 16, block 256
// ---------------------------------------------------------------------------
__global__ __launch_bounds__(256) void topk_kernel(
    const float* __restrict__ measure, int* __restrict__ qlist)
{
    const int bh = blockIdx.x;
    __shared__ float m[L_];
    __shared__ int cnt;
    if (threadIdx.x == 0) cnt = 0;
    for (int i = threadIdx.x; i < L_; i += 256) m[i] = measure[bh * L_ + i];
    __syncthreads();
    for (int i = threadIdx.x; i < L_; i += 256) {
        float mi = m[i];
        int rank = 0;
        for (int j = 0; j < L_; j++) {
            float mj = m[j];
            rank += (mj > mi) || (mj == mi && j < i);
        }
        if (rank < NQ_) {
            int pos = atomicAdd(&cnt, 1);
            qlist[bh * NQ_ + pos] = i;
        }
    }
}

// ---------------------------------------------------------------------------
// K5: fill attn_out (layout [b, l, d] with d = h*36+dd) with Vmean broadcast.
// ---------------------------------------------------------------------------
__global__ __launch_bounds__(256) void fill_kernel(
    const float* __restrict__ Vmean, float* __restrict__ attn_out)
{
    int idx = blockIdx.x * blockDim.x + threadIdx.x;
    if (idx >= B_ * L_ * D_) return;
    int d = idx % D_;
    int bl = idx / D_;
    int b = bl / L_;
    int h = d / DIM_, dd = d % DIM_;
    attn_out[idx] = Vmean[(b * H_ + h) * DIM_ + dd];
}

// ---------------------------------------------------------------------------
// K6: dense attention for selected queries. One wave per (bh, slot).
// scores in registers (16/lane), softmax via cross-lane reduce,
// V-weighted accumulate with LDS partial reduction (stride-37 padded).
// grid 1000, block 256 (4 waves)
// ---------------------------------------------------------------------------
__global__ __launch_bounds__(256) void attn_kernel(
    const float* __restrict__ Q, const float* __restrict__ K,
    const float* __restrict__ V, const int* __restrict__ qlist,
    float* __restrict__ attn_out)
{
    const int w = threadIdx.x >> 6;
    const int lane = threadIdx.x & 63;
    const int wid = blockIdx.x * 4 + w;     // 0..3999
    const int bh = wid / NQ_;
    const int slot = wid % NQ_;
    const int qidx = qlist[bh * NQ_ + slot];

    __shared__ float qs[4][DIM_];
    __shared__ float accs[4][64][DIM_ + 1];   // pad to 37 -> conflict-free

    if (lane < DIM_) qs[w][lane] = Q[(bh * L_ + qidx) * DIM_ + lane];
    __syncthreads();

    const float* Kb = K + (size_t)bh * L_ * DIM_;
    const float* Vb = V + (size_t)bh * L_ * DIM_;
    const float scale = (float)(1.0 / 6.0);   // 1/sqrt(36)

    float sc[16];
    float mx = -1e30f;
#pragma unroll
    for (int i = 0; i < 16; i++) {
        int lk = lane + i * 64;
        if (lk < L_) {
            const float* kr = Kb + lk * DIM_;
            float acc = 0.f;
#pragma unroll
            for (int d = 0; d < DIM_; d++) acc += qs[w][d] * kr[d];
            acc *= scale;
            sc[i] = acc;
            mx = fmaxf(mx, acc);
        }
    }
#pragma unroll
    for (int off = 32; off; off >>= 1) mx = fmaxf(mx, __shfl_xor(mx, off));

    float acc[DIM_];
#pragma unroll
    for (int d = 0; d < DIM_; d++) acc[d] = 0.f;
    float sum = 0.f;
#pragma unroll
    for (int i = 0; i < 16; i++) {
        int lk = lane + i * 64;
        if (lk < L_) {
            float e = __expf(sc[i] - mx);
            sum += e;
            const float* vr = Vb + lk * DIM_;
#pragma unroll
            for (int d = 0; d < DIM_; d++) acc[d] += e * vr[d];
        }
    }
#pragma unroll
    for (int off = 32; off; off >>= 1) sum += __shfl_xor(sum, off);

#pragma unroll
    for (int d = 0; d < DIM_; d++) accs[w][lane][d] = acc[d];
    __syncthreads();

    if (lane < DIM_) {
        float t = 0.f;
        for (int l2 = 0; l2 < 64; l2++) t += accs[w][l2][lane];
        int b = bh / H_, h = bh % H_;
        attn_out[(b * L_ + qidx) * D_ + h * DIM_ + lane] = t / sum;
    }
}

// ---------------------------------------------------------------------------
// K7: LN1: h1 = LayerNorm(x + attn_out) per row of 288. One wave per row.
// grid 2000, block 64
// ---------------------------------------------------------------------------
__global__ __launch_bounds__(64) void ln1_kernel(
    const float* __restrict__ x, const float* __restrict__ attn,
    const float* __restrict__ g, const float* __restrict__ bb,
    float* __restrict__ h1)
{
    const int row = blockIdx.x;
    const int lane = threadIdx.x;
    const float* xr = x + row * D_;
    const float* ar = attn + row * D_;

    float vals[5];
    float s = 0.f;
#pragma unroll
    for (int i = 0; i < 5; i++) {
        int j = lane + i * 64;
        float v = (j < D_) ? (xr[j] + ar[j]) : 0.f;
        vals[i] = v;
        s += v;
    }
#pragma unroll
    for (int off = 32; off; off >>= 1) s += __shfl_xor(s, off);
    float mu = s * (1.0f / D_);

    float vs = 0.f;
#pragma unroll
    for (int i = 0; i < 5; i++) {
        int j = lane + i * 64;
        if (j < D_) { float dd = vals[i] - mu; vs += dd * dd; }
    }
#pragma unroll
    for (int off = 32; off; off >>= 1) vs += __shfl_xor(vs, off);
    float rstd = rsqrtf(vs * (1.0f / D_) + EPS_);

#pragma unroll
    for (int i = 0; i < 5; i++) {
        int j = lane + i * 64;
        if (j < D_) h1[row * D_ + j] = (vals[i] - mu) * rstd * g[j] + bb[j];
    }
}

// ---------------------------------------------------------------------------
// K8: fused FFN (gelu(h1@W1.T+b1) -> gelu(.@W2.T+b2)) + residual + LN2.
// 8 rows per block (weight-row reuse). grid 250, block 256
// ---------------------------------------------------------------------------
__global__ __launch_bounds__(256) void ffn_ln_kernel(
    const float* __restrict__ h1,
    const float* __restrict__ W1, const float* __restrict__ b1,
    const float* __restrict__ W2, const float* __restrict__ b2,
    const float* __restrict__ g, const float* __restrict__ bb,
    float* __restrict__ out)
{
    constexpr int R = 8;
    __shared__ float h1s[R][D_];
    __shared__ float f1s[R][DFF_];
    __shared__ float ys[R][D_];
    const int base = blockIdx.x * R;
    const int tid = threadIdx.x;

    for (int idx = tid; idx < R * D_; idx += 256) {
        int r = idx / D_, j = idx % D_;
        h1s[r][j] = h1[(base + r) * D_ + j];
    }
    __syncthreads();

    // FFN layer 1: [R,288] x [288,576]^T -> gelu -> f1s
    for (int j = tid; j < DFF_; j += 256) {
        const float* wrow = W1 + j * D_;
        float bias = b1[j];
        float acc[R];
#pragma unroll
        for (int r = 0; r < R; r++) acc[r] = bias;
        for (int d = 0; d < D_; d++) {
            float wv = wrow[d];
#pragma unroll
            for (int r = 0; r < R; r++) acc[r] += h1s[r][d] * wv;
        }
#pragma unroll
        for (int r = 0; r < R; r++) f1s[r][j] = gelu_exact(acc[r]);
    }
    __syncthreads();

    // FFN layer 2: [R,576] x [576,288]^T -> gelu -> + h1 -> ys
    for (int j = tid; j < D_; j += 256) {
        const float* wrow = W2 + j * DFF_;
        float bias = b2[j];
        float acc[R];
#pragma unroll
        for (int r = 0; r < R; r++) acc[r] = bias;
        for (int d = 0; d < DFF_; d++) {
            float wv = wrow[d];
#pragma unroll
            for (int r = 0; r < R; r++) acc[r] += f1s[r][d] * wv;
        }
#pragma unroll
        for (int r = 0; r < R; r++) ys[r][j] = gelu_exact(acc[r]) + h1s[r][j];
    }
    __syncthreads();

    // LN2 per row: wave w handles rows w and w+4
    const int w = tid >> 6;
    const int lane = tid & 63;
    for (int r = w; r < R; r += 4) {
        float s = 0.f, ss = 0.f;
#pragma unroll
        for (int i = 0; i < 5; i++) {
            int j = lane + i * 64;
            if (j < D_) { float y = ys[r][j]; s += y; ss += y * y; }
        }
#pragma unroll
        for (int off = 32; off; off >>= 1) {
            s += __shfl_xor(s, off);
            ss += __shfl_xor(ss, off);
        }
        float mu = s * (1.0f / D_);
        float var = ss * (1.0f / D_) - mu * mu;
        float rstd = rsqrtf(var + EPS_);
        int row = base + r;
#pragma unroll
        for (int i = 0; i < 5; i++) {
            int j = lane + i * 64;
            if (j < D_) out[row * D_ + j] = (ys[r][j] - mu) * rstd * g[j] + bb[j];
        }
    }
}

// ---------------------------------------------------------------------------
extern "C" void kernel_launch(void* const* d_in, const int* in_sizes, int n_in,
                              void* d_out, int out_size, void* d_ws, size_t ws_size,
                              hipStream_t stream)
{
    const float* x         = (const float*)d_in[0];
    const int*   index_key = (const int*)  d_in[1];
    const float* Wq = (const float*)d_in[2];
    const float* bq = (const float*)d_in[3];
    const float* Wk = (const float*)d_in[4];
    const float* bk = (const float*)d_in[5];
    const float* Wv = (const float*)d_in[6];
    const float* bv = (const float*)d_in[7];
    const float* W1 = (const float*)d_in[8];
    const float* b1 = (const float*)d_in[9];
    const float* W2 = (const float*)d_in[10];
    const float* b2 = (const float*)d_in[11];
    const float* ln1_g = (const float*)d_in[12];
    const float* ln1_b = (const float*)d_in[13];
    const float* ln2_g = (const float*)d_in[14];
    const float* ln2_b = (const float*)d_in[15];
    float* out = (float*)d_out;

    // workspace carve (floats)
    float* Q        = (float*)d_ws;              // 576000
    float* K        = Q + (size_t)BH_ * L_ * DIM_;
    float* V        = K + (size_t)BH_ * L_ * DIM_;
    float* Vmean    = V + (size_t)BH_ * L_ * DIM_;   // 576
    float* measure  = Vmean + BH_ * DIM_;            // 16000
    float* attn_out = measure + BH_ * L_;            // 576000
    float* h1       = attn_out + (size_t)B_ * L_ * D_;
    int*   qlist    = (int*)(h1 + (size_t)B_ * L_ * D_);  // 4000 ints

    qkv_kernel<<<250, 256, 0, stream>>>(x, Wq, bq, Wk, bk, Wv, bv, Q, K, V);
    vmean_kernel<<<3, 256, 0, stream>>>(V, Vmean);
    measure_kernel<<<4000, 256, 0, stream>>>(Q, K, index_key, measure);
    topk_kernel<<<16, 256, 0, stream>>>(measure, qlist);
    fill_kernel<<<2250, 256, 0, stream>>>(Vmean, attn_out);
    attn_kernel<<<1000, 256, 0, stream>>>(Q, K, V, qlist, attn_out);
    ln1_kernel<<<2000, 64, 0, stream>>>(x, attn_out, ln1_g, ln1_b, h1);
    ffn_ln_kernel<<<250, 256, 0, stream>>>(h1, W1, b1, W2, b2, ln2_g, ln2_b, out);
}

// Round 2
// 509.831 us; speedup vs baseline: 1.1290x; 1.1290x over previous
//
#include <hip/hip_runtime.h>
#include <hip/hip_bf16.h>
#include <math.h>

// Problem constants
#define B_ 2
#define L_ 1000
#define D_ 288
#define H_ 8
#define DIM_ 36
#define DFF_ 576
#define KS_ 250
#define NQ_ 250
#define BH_ (B_ * H_)
#define EPS_ 1e-5f
#define NCHUNK_ 8
#define CHUNK_ (L_ / NCHUNK_)   // 125 keys per chunk
#define PSTRIDE_ 40             // partial row: 36 acc + 1 sum, padded to 40 (16B align)

__device__ __forceinline__ float gelu_exact(float x) {
    return 0.5f * x * (1.0f + erff(x * 0.70710678118654752f));
}

__device__ __forceinline__ float dot4(float4 a, float4 b) {
    return a.x * b.x + a.y * b.y + a.z * b.z + a.w * b.w;
}

// ---------------------------------------------------------------------------
// K1: QKV projection. 8 rows/block, split output columns into 2 halves.
// grid 500, block 256
// ---------------------------------------------------------------------------
__global__ __launch_bounds__(256) void qkv_kernel(
    const float* __restrict__ x,
    const float* __restrict__ Wq, const float* __restrict__ bq,
    const float* __restrict__ Wk, const float* __restrict__ bk,
    const float* __restrict__ Wv, const float* __restrict__ bv,
    float* __restrict__ Q, float* __restrict__ K, float* __restrict__ V)
{
    constexpr int R = 8;
    __shared__ float xs[R][D_];
    const int base = (blockIdx.x >> 1) * R;   // base row in [0, 2000)
    const int half = blockIdx.x & 1;
    const int tid = threadIdx.x;

    // coalesced float4 stage of 8 contiguous rows (2304 floats)
    const float4* xsrc = (const float4*)(x + (size_t)base * D_);
    float4* xdst = (float4*)&xs[0][0];
    for (int idx = tid; idx < R * D_ / 4; idx += 256) xdst[idx] = xsrc[idx];
    __syncthreads();

    const float* Ws[3] = {Wq, Wk, Wv};
    const float* Bs[3] = {bq, bk, bv};
    float* Os[3] = {Q, K, V};

    const int j0 = half * 432;
    for (int j = j0 + tid; j < j0 + 432; j += 256) {
        int which = j / D_, jj = j % D_;
        const float4* w4 = (const float4*)(Ws[which] + (size_t)jj * D_);
        float bias = Bs[which][jj];
        float acc[R];
#pragma unroll
        for (int r = 0; r < R; r++) acc[r] = bias;
        for (int d4 = 0; d4 < D_ / 4; d4++) {
            float4 wv = w4[d4];
#pragma unroll
            for (int r = 0; r < R; r++) {
                float4 xv = *(const float4*)&xs[r][d4 * 4];
                acc[r] += dot4(xv, wv);
            }
        }
        int h = jj / DIM_, dd = jj % DIM_;
        float* o = Os[which];
#pragma unroll
        for (int r = 0; r < R; r++) {
            int row = base + r;
            int b = row / L_, l = row % L_;
            o[((size_t)(b * H_ + h) * L_ + l) * DIM_ + dd] = acc[r];
        }
    }
}

// ---------------------------------------------------------------------------
// K2: Vmean[bh, d]. Block per bh, 7 l-groups x 36 d = 252 active threads.
// ---------------------------------------------------------------------------
__global__ __launch_bounds__(256) void vmean_kernel(
    const float* __restrict__ V, float* __restrict__ Vmean)
{
    const int bh = blockIdx.x;
    const int tid = threadIdx.x;
    __shared__ float red[7][DIM_];
    if (tid < 252) {
        int g = tid / DIM_, d = tid % DIM_;
        const float* base = V + (size_t)bh * L_ * DIM_;
        float s = 0.f;
        for (int l = g; l < L_; l += 7) s += base[l * DIM_ + d];
        red[g][d] = s;
    }
    __syncthreads();
    if (tid < DIM_) {
        float s = 0.f;
#pragma unroll
        for (int g = 0; g < 7; g++) s += red[g][tid];
        Vmean[bh * DIM_ + tid] = s * (1.0f / L_);
    }
}

// ---------------------------------------------------------------------------
// K3: sparsity measure. One wave per (bh, l). q in registers (wave-uniform
// load), sampled K rows gathered as 9x float4.
// grid 4000, block 256 (4 waves)
// ---------------------------------------------------------------------------
__global__ __launch_bounds__(256) void measure_kernel(
    const float* __restrict__ Q, const float* __restrict__ K,
    const int* __restrict__ index_key, float* __restrict__ measure)
{
    const int w = threadIdx.x >> 6;
    const int lane = threadIdx.x & 63;
    const int wid = blockIdx.x * 4 + w;      // 0..15999
    const int bh = wid / L_;
    const int l = wid % L_;

    const float4* qp = (const float4*)(Q + ((size_t)bh * L_ + l) * DIM_);
    float4 q[9];
#pragma unroll
    for (int i = 0; i < 9; i++) q[i] = qp[i];

    const int* ik = index_key + l * KS_;
    const float* Kb = K + (size_t)bh * L_ * DIM_;

    float mx = -1e30f, sm = 0.f;
    for (int s = lane; s < KS_; s += 64) {
        int kidx = ik[s];
        const float4* k4 = (const float4*)(Kb + (size_t)kidx * DIM_);
        float acc = 0.f;
#pragma unroll
        for (int i = 0; i < 9; i++) acc += dot4(q[i], k4[i]);
        mx = fmaxf(mx, acc);
        sm += acc;
    }
#pragma unroll
    for (int off = 32; off; off >>= 1) {
        mx = fmaxf(mx, __shfl_xor(mx, off));
        sm += __shfl_xor(sm, off);
    }
    if (lane == 0) measure[wid] = mx - sm * (1.0f / (float)L_);
}

// ---------------------------------------------------------------------------
// K4: top-NQ per (b,h) via O(N^2) rank counting. grid 16, block 256
// ---------------------------------------------------------------------------
__global__ __launch_bounds__(256) void topk_kernel(
    const float* __restrict__ measure, int* __restrict__ qlist)
{
    const int bh = blockIdx.x;
    __shared__ float m[L_];
    __shared__ int cnt;
    if (threadIdx.x == 0) cnt = 0;
    for (int i = threadIdx.x; i < L_; i += 256) m[i] = measure[bh * L_ + i];
    __syncthreads();
    for (int i = threadIdx.x; i < L_; i += 256) {
        float mi = m[i];
        int rank = 0;
        for (int j = 0; j < L_; j++) {
            float mj = m[j];
            rank += (mj > mi) || (mj == mi && j < i);
        }
        if (rank < NQ_) {
            int pos = atomicAdd(&cnt, 1);
            qlist[bh * NQ_ + pos] = i;
        }
    }
}

// ---------------------------------------------------------------------------
// K5: fill attn_out with Vmean broadcast.
// ---------------------------------------------------------------------------
__global__ __launch_bounds__(256) void fill_kernel(
    const float* __restrict__ Vmean, float* __restrict__ attn_out)
{
    int idx = blockIdx.x * blockDim.x + threadIdx.x;
    if (idx >= B_ * L_ * D_) return;
    int d = idx % D_;
    int bl = idx / D_;
    int b = bl / L_;
    int h = d / DIM_, dd = d % DIM_;
    attn_out[idx] = Vmean[(b * H_ + h) * DIM_ + dd];
}

// ---------------------------------------------------------------------------
// K6: attention partials. Block = (bh, key-chunk); thread = selected query.
// All threads process the SAME key -> wave-uniform K/V addresses (scalarized
// broadcast loads). Raw-exp softmax (no max; scores bounded ~3.5) so chunk
// partials are additive. grid 128, block 256 (250 active).
// ---------------------------------------------------------------------------
__global__ __launch_bounds__(256) void attn_part_kernel(
    const float* __restrict__ Q, const float* __restrict__ K,
    const float* __restrict__ V, const int* __restrict__ qlist,
    float* __restrict__ part)
{
    const int bh = blockIdx.x / NCHUNK_;
    const int chunk = blockIdx.x % NCHUNK_;
    const int slot = threadIdx.x;
    if (slot >= NQ_) return;

    const int qidx = qlist[bh * NQ_ + slot];
    const float4* qp = (const float4*)(Q + ((size_t)bh * L_ + qidx) * DIM_);
    float4 q[9];
#pragma unroll
    for (int i = 0; i < 9; i++) q[i] = qp[i];

    const float* Kb = K + (size_t)bh * L_ * DIM_;
    const float* Vb = V + (size_t)bh * L_ * DIM_;
    const float scale = (float)(1.0 / 6.0);

    float4 acc[9];
#pragma unroll
    for (int i = 0; i < 9; i++) acc[i] = make_float4(0.f, 0.f, 0.f, 0.f);
    float sum = 0.f;

    const int k0 = chunk * CHUNK_;
    for (int j = 0; j < CHUNK_; j++) {
        const int key = k0 + j;                       // wave-uniform
        const float4* kp = (const float4*)(Kb + (size_t)key * DIM_);
        float s = 0.f;
#pragma unroll
        for (int i = 0; i < 9; i++) s += dot4(q[i], kp[i]);
        float e = __expf(s * scale);
        sum += e;
        const float4* vp = (const float4*)(Vb + (size_t)key * DIM_);
#pragma unroll
        for (int i = 0; i < 9; i++) {
            float4 vv = vp[i];
            acc[i].x += e * vv.x;
            acc[i].y += e * vv.y;
            acc[i].z += e * vv.z;
            acc[i].w += e * vv.w;
        }
    }

    float* p = part + ((size_t)(bh * NQ_ + slot) * NCHUNK_ + chunk) * PSTRIDE_;
#pragma unroll
    for (int i = 0; i < 9; i++) ((float4*)p)[i] = acc[i];
    p[DIM_] = sum;
}

// ---------------------------------------------------------------------------
// K7: combine chunk partials -> attn_out for selected queries.
// thread per (bh, slot, d): 144000 threads.
// ---------------------------------------------------------------------------
__global__ __launch_bounds__(256) void combine_kernel(
    const float* __restrict__ part, const int* __restrict__ qlist,
    float* __restrict__ attn_out)
{
    int idx = blockIdx.x * blockDim.x + threadIdx.x;
    if (idx >= BH_ * NQ_ * DIM_) return;
    int d = idx % DIM_;
    int bhslot = idx / DIM_;
    int bh = bhslot / NQ_, slot = bhslot % NQ_;
    const float* base = part + (size_t)bhslot * NCHUNK_ * PSTRIDE_;
    float a = 0.f, s = 0.f;
#pragma unroll
    for (int c = 0; c < NCHUNK_; c++) {
        a += base[c * PSTRIDE_ + d];
        s += base[c * PSTRIDE_ + DIM_];
    }
    int qidx = qlist[bh * NQ_ + slot];
    int b = bh / H_, h = bh % H_;
    attn_out[((size_t)b * L_ + qidx) * D_ + h * DIM_ + d] = a / s;
}

// ---------------------------------------------------------------------------
// K8: LN1: h1 = LayerNorm(x + attn_out). One wave per row. grid 2000, block 64
// ---------------------------------------------------------------------------
__global__ __launch_bounds__(64) void ln1_kernel(
    const float* __restrict__ x, const float* __restrict__ attn,
    const float* __restrict__ g, const float* __restrict__ bb,
    float* __restrict__ h1)
{
    const int row = blockIdx.x;
    const int lane = threadIdx.x;
    const float* xr = x + (size_t)row * D_;
    const float* ar = attn + (size_t)row * D_;

    float vals[5];
    float s = 0.f;
#pragma unroll
    for (int i = 0; i < 5; i++) {
        int j = lane + i * 64;
        float v = (j < D_) ? (xr[j] + ar[j]) : 0.f;
        vals[i] = v;
        s += v;
    }
#pragma unroll
    for (int off = 32; off; off >>= 1) s += __shfl_xor(s, off);
    float mu = s * (1.0f / D_);

    float vs = 0.f;
#pragma unroll
    for (int i = 0; i < 5; i++) {
        int j = lane + i * 64;
        if (j < D_) { float dd = vals[i] - mu; vs += dd * dd; }
    }
#pragma unroll
    for (int off = 32; off; off >>= 1) vs += __shfl_xor(vs, off);
    float rstd = rsqrtf(vs * (1.0f / D_) + EPS_);

#pragma unroll
    for (int i = 0; i < 5; i++) {
        int j = lane + i * 64;
        if (j < D_) h1[(size_t)row * D_ + j] = (vals[i] - mu) * rstd * g[j] + bb[j];
    }
}

// ---------------------------------------------------------------------------
// K9: fused FFN + residual + LN2. 8 rows/block, float4 LDS/weight reads.
// grid 250, block 256
// ---------------------------------------------------------------------------
__global__ __launch_bounds__(256) void ffn_ln_kernel(
    const float* __restrict__ h1,
    const float* __restrict__ W1, const float* __restrict__ b1,
    const float* __restrict__ W2, const float* __restrict__ b2,
    const float* __restrict__ g, const float* __restrict__ bb,
    float* __restrict__ out)
{
    constexpr int R = 8;
    __shared__ float h1s[R][D_];
    __shared__ float f1s[R][DFF_];
    __shared__ float ys[R][D_];
    const int base = blockIdx.x * R;
    const int tid = threadIdx.x;

    const float4* hsrc = (const float4*)(h1 + (size_t)base * D_);
    float4* hdst = (float4*)&h1s[0][0];
    for (int idx = tid; idx < R * D_ / 4; idx += 256) hdst[idx] = hsrc[idx];
    __syncthreads();

    // FFN layer 1
    for (int j = tid; j < DFF_; j += 256) {
        const float4* w4 = (const float4*)(W1 + (size_t)j * D_);
        float bias = b1[j];
        float acc[R];
#pragma unroll
        for (int r = 0; r < R; r++) acc[r] = bias;
        for (int d4 = 0; d4 < D_ / 4; d4++) {
            float4 wv = w4[d4];
#pragma unroll
            for (int r = 0; r < R; r++) {
                float4 hv = *(const float4*)&h1s[r][d4 * 4];
                acc[r] += dot4(hv, wv);
            }
        }
#pragma unroll
        for (int r = 0; r < R; r++) f1s[r][j] = gelu_exact(acc[r]);
    }
    __syncthreads();

    // FFN layer 2 + residual
    for (int j = tid; j < D_; j += 256) {
        const float4* w4 = (const float4*)(W2 + (size_t)j * DFF_);
        float bias = b2[j];
        float acc[R];
#pragma unroll
        for (int r = 0; r < R; r++) acc[r] = bias;
        for (int d4 = 0; d4 < DFF_ / 4; d4++) {
            float4 wv = w4[d4];
#pragma unroll
            for (int r = 0; r < R; r++) {
                float4 fv = *(const float4*)&f1s[r][d4 * 4];
                acc[r] += dot4(fv, wv);
            }
        }
#pragma unroll
        for (int r = 0; r < R; r++) ys[r][j] = gelu_exact(acc[r]) + h1s[r][j];
    }
    __syncthreads();

    // LN2 per row
    const int w = tid >> 6;
    const int lane = tid & 63;
    for (int r = w; r < R; r += 4) {
        float s = 0.f, ss = 0.f;
#pragma unroll
        for (int i = 0; i < 5; i++) {
            int j = lane + i * 64;
            if (j < D_) { float y = ys[r][j]; s += y; ss += y * y; }
        }
#pragma unroll
        for (int off = 32; off; off >>= 1) {
            s += __shfl_xor(s, off);
            ss += __shfl_xor(ss, off);
        }
        float mu = s * (1.0f / D_);
        float var = ss * (1.0f / D_) - mu * mu;
        float rstd = rsqrtf(var + EPS_);
        int row = base + r;
#pragma unroll
        for (int i = 0; i < 5; i++) {
            int j = lane + i * 64;
            if (j < D_) out[(size_t)row * D_ + j] = (ys[r][j] - mu) * rstd * g[j] + bb[j];
        }
    }
}

// ---------------------------------------------------------------------------
extern "C" void kernel_launch(void* const* d_in, const int* in_sizes, int n_in,
                              void* d_out, int out_size, void* d_ws, size_t ws_size,
                              hipStream_t stream)
{
    const float* x         = (const float*)d_in[0];
    const int*   index_key = (const int*)  d_in[1];
    const float* Wq = (const float*)d_in[2];
    const float* bq = (const float*)d_in[3];
    const float* Wk = (const float*)d_in[4];
    const float* bk = (const float*)d_in[5];
    const float* Wv = (const float*)d_in[6];
    const float* bv = (const float*)d_in[7];
    const float* W1 = (const float*)d_in[8];
    const float* b1 = (const float*)d_in[9];
    const float* W2 = (const float*)d_in[10];
    const float* b2 = (const float*)d_in[11];
    const float* ln1_g = (const float*)d_in[12];
    const float* ln1_b = (const float*)d_in[13];
    const float* ln2_g = (const float*)d_in[14];
    const float* ln2_b = (const float*)d_in[15];
    float* out = (float*)d_out;

    // workspace carve (floats)
    float* Q        = (float*)d_ws;                      // 576000
    float* K        = Q + (size_t)BH_ * L_ * DIM_;       // 576000
    float* V        = K + (size_t)BH_ * L_ * DIM_;       // 576000
    float* Vmean    = V + (size_t)BH_ * L_ * DIM_;       // 576
    float* measure  = Vmean + BH_ * DIM_;                // 16000
    float* attn_out = measure + BH_ * L_;                // 576000
    float* h1       = attn_out + (size_t)B_ * L_ * D_;   // 576000
    float* part     = h1 + (size_t)B_ * L_ * D_;         // 16*250*8*40 = 1280000
    int*   qlist    = (int*)(part + (size_t)BH_ * NQ_ * NCHUNK_ * PSTRIDE_); // 4000

    qkv_kernel<<<500, 256, 0, stream>>>(x, Wq, bq, Wk, bk, Wv, bv, Q, K, V);
    vmean_kernel<<<BH_, 256, 0, stream>>>(V, Vmean);
    measure_kernel<<<4000, 256, 0, stream>>>(Q, K, index_key, measure);
    topk_kernel<<<BH_, 256, 0, stream>>>(measure, qlist);
    fill_kernel<<<(B_ * L_ * D_ + 255) / 256, 256, 0, stream>>>(Vmean, attn_out);
    attn_part_kernel<<<BH_ * NCHUNK_, 256, 0, stream>>>(Q, K, V, qlist, part);
    combine_kernel<<<(BH_ * NQ_ * DIM_ + 255) / 256, 256, 0, stream>>>(part, qlist, attn_out);
    ln1_kernel<<<B_ * L_, 64, 0, stream>>>(x, attn_out, ln1_g, ln1_b, h1);
    ffn_ln_kernel<<<250, 256, 0, stream>>>(h1, W1, b1, W2, b2, ln2_g, ln2_b, out);
}

// Round 3
// 490.515 us; speedup vs baseline: 1.1734x; 1.0394x over previous
//
#include <hip/hip_runtime.h>
#include <hip/hip_bf16.h>
#include <math.h>

// Problem constants
#define B_ 2
#define L_ 1000
#define D_ 288
#define H_ 8
#define DIM_ 36
#define DFF_ 576
#define KS_ 250
#define NQ_ 250
#define BH_ (B_ * H_)
#define EPS_ 1e-5f
#define NCHUNK_ 8
#define CHUNK_ (L_ / NCHUNK_)   // 125 keys per chunk
#define PSTRIDE_ 40             // partial row: 36 acc + 1 sum, padded to 40

__device__ __forceinline__ float gelu_exact(float x) {
    return 0.5f * x * (1.0f + erff(x * 0.70710678118654752f));
}

__device__ __forceinline__ float dot4(float4 a, float4 b) {
    return a.x * b.x + a.y * b.y + a.z * b.z + a.w * b.w;
}

// ---------------------------------------------------------------------------
// K1: QKV projection. 8 rows/block; thread tid computes column tid of
// Wq, Wk AND Wv (3 independent weight streams -> ILP). grid 250, block 320
// (288 active in compute).
// ---------------------------------------------------------------------------
__global__ __launch_bounds__(320) void qkv_kernel(
    const float* __restrict__ x,
    const float* __restrict__ Wq, const float* __restrict__ bq,
    const float* __restrict__ Wk, const float* __restrict__ bk,
    const float* __restrict__ Wv, const float* __restrict__ bv,
    float* __restrict__ Q, float* __restrict__ K, float* __restrict__ V)
{
    constexpr int R = 8;
    __shared__ float xs[R][D_];
    const int base = blockIdx.x * R;
    const int tid = threadIdx.x;

    const float4* xsrc = (const float4*)(x + (size_t)base * D_);
    float4* xdst = (float4*)&xs[0][0];
    for (int i = tid; i < R * D_ / 4; i += 320) xdst[i] = xsrc[i];
    __syncthreads();

    if (tid < D_) {
        const float4* wq4 = (const float4*)(Wq + (size_t)tid * D_);
        const float4* wk4 = (const float4*)(Wk + (size_t)tid * D_);
        const float4* wv4 = (const float4*)(Wv + (size_t)tid * D_);
        float aq[R], ak[R], av[R];
        float biasq = bq[tid], biask = bk[tid], biasv = bv[tid];
#pragma unroll
        for (int r = 0; r < R; r++) { aq[r] = biasq; ak[r] = biask; av[r] = biasv; }
        for (int d4 = 0; d4 < D_ / 4; d4++) {
            float4 wqv = wq4[d4], wkv = wk4[d4], wvv = wv4[d4];
#pragma unroll
            for (int r = 0; r < R; r++) {
                float4 hv = *(const float4*)&xs[r][d4 * 4];
                aq[r] += dot4(hv, wqv);
                ak[r] += dot4(hv, wkv);
                av[r] += dot4(hv, wvv);
            }
        }
        const int h = tid / DIM_, dd = tid % DIM_;
#pragma unroll
        for (int r = 0; r < R; r++) {
            int row = base + r;
            int b = row / L_, l = row % L_;
            size_t o = ((size_t)(b * H_ + h) * L_ + l) * DIM_ + dd;
            Q[o] = aq[r]; K[o] = ak[r]; V[o] = av[r];
        }
    }
}

// ---------------------------------------------------------------------------
// K2: Vmean[bh, d]. Block per bh.
// ---------------------------------------------------------------------------
__global__ __launch_bounds__(256) void vmean_kernel(
    const float* __restrict__ V, float* __restrict__ Vmean)
{
    const int bh = blockIdx.x;
    const int tid = threadIdx.x;
    __shared__ float red[7][DIM_];
    if (tid < 252) {
        int g = tid / DIM_, d = tid % DIM_;
        const float* base = V + (size_t)bh * L_ * DIM_;
        float s = 0.f;
        for (int l = g; l < L_; l += 7) s += base[l * DIM_ + d];
        red[g][d] = s;
    }
    __syncthreads();
    if (tid < DIM_) {
        float s = 0.f;
#pragma unroll
        for (int g = 0; g < 7; g++) s += red[g][tid];
        Vmean[bh * DIM_ + tid] = s * (1.0f / L_);
    }
}

// ---------------------------------------------------------------------------
// K3: sparsity measure. One wave per (bh, l).
// ---------------------------------------------------------------------------
__global__ __launch_bounds__(256) void measure_kernel(
    const float* __restrict__ Q, const float* __restrict__ K,
    const int* __restrict__ index_key, float* __restrict__ measure)
{
    const int w = threadIdx.x >> 6;
    const int lane = threadIdx.x & 63;
    const int wid = blockIdx.x * 4 + w;      // 0..15999
    const int bh = wid / L_;
    const int l = wid % L_;

    const float4* qp = (const float4*)(Q + ((size_t)bh * L_ + l) * DIM_);
    float4 q[9];
#pragma unroll
    for (int i = 0; i < 9; i++) q[i] = qp[i];

    const int* ik = index_key + l * KS_;
    const float* Kb = K + (size_t)bh * L_ * DIM_;

    float mx = -1e30f, sm = 0.f;
#pragma unroll
    for (int s = lane; s < KS_; s += 64) {
        int kidx = ik[s];
        const float4* k4 = (const float4*)(Kb + (size_t)kidx * DIM_);
        float acc = 0.f;
#pragma unroll
        for (int i = 0; i < 9; i++) acc += dot4(q[i], k4[i]);
        mx = fmaxf(mx, acc);
        sm += acc;
    }
#pragma unroll
    for (int off = 32; off; off >>= 1) {
        mx = fmaxf(mx, __shfl_xor(mx, off));
        sm += __shfl_xor(sm, off);
    }
    if (lane == 0) measure[wid] = mx - sm * (1.0f / (float)L_);
}

// ---------------------------------------------------------------------------
// K4: top-NQ per (b,h) via rank counting; grid 64 (bh x quarter),
// global atomic counter per bh (zeroed via memsetAsync before launch).
// ---------------------------------------------------------------------------
__global__ __launch_bounds__(256) void topk_kernel(
    const float* __restrict__ measure, int* __restrict__ qlist,
    int* __restrict__ qcnt)
{
    const int bh = blockIdx.x >> 2;
    const int quarter = blockIdx.x & 3;
    __shared__ float m[L_];
    for (int i = threadIdx.x; i < L_; i += 256) m[i] = measure[bh * L_ + i];
    __syncthreads();
    const int i = quarter * 250 + threadIdx.x;
    if (threadIdx.x < 250) {
        float mi = m[i];
        int rank = 0;
        for (int j = 0; j < L_; j++) {
            float mj = m[j];
            rank += (mj > mi) || (mj == mi && j < i);
        }
        if (rank < NQ_) {
            int pos = atomicAdd(&qcnt[bh], 1);
            qlist[bh * NQ_ + pos] = i;
        }
    }
}

// ---------------------------------------------------------------------------
// K5: fill attn_out with Vmean broadcast.
// ---------------------------------------------------------------------------
__global__ __launch_bounds__(256) void fill_kernel(
    const float* __restrict__ Vmean, float* __restrict__ attn_out)
{
    int idx = blockIdx.x * blockDim.x + threadIdx.x;
    if (idx >= B_ * L_ * D_) return;
    int d = idx % D_;
    int bl = idx / D_;
    int b = bl / L_;
    int h = d / DIM_, dd = d % DIM_;
    attn_out[idx] = Vmean[(b * H_ + h) * DIM_ + dd];
}

// ---------------------------------------------------------------------------
// K6: attention partials. Block = (bh, key-chunk); thread = selected query.
// Wave-uniform K/V addresses; raw-exp softmax partials are additive.
// grid 128, block 256 (250 active).
// ---------------------------------------------------------------------------
__global__ __launch_bounds__(256) void attn_part_kernel(
    const float* __restrict__ Q, const float* __restrict__ K,
    const float* __restrict__ V, const int* __restrict__ qlist,
    float* __restrict__ part)
{
    const int bh = blockIdx.x / NCHUNK_;
    const int chunk = blockIdx.x % NCHUNK_;
    const int slot = threadIdx.x;
    if (slot >= NQ_) return;

    const int qidx = qlist[bh * NQ_ + slot];
    const float4* qp = (const float4*)(Q + ((size_t)bh * L_ + qidx) * DIM_);
    float4 q[9];
#pragma unroll
    for (int i = 0; i < 9; i++) q[i] = qp[i];

    const float* Kb = K + (size_t)bh * L_ * DIM_;
    const float* Vb = V + (size_t)bh * L_ * DIM_;
    const float scale = (float)(1.0 / 6.0);

    float4 acc[9];
#pragma unroll
    for (int i = 0; i < 9; i++) acc[i] = make_float4(0.f, 0.f, 0.f, 0.f);
    float sum = 0.f;

    const int k0 = chunk * CHUNK_;
    for (int j = 0; j < CHUNK_; j++) {
        const int key = k0 + j;                       // wave-uniform
        const float4* kp = (const float4*)(Kb + (size_t)key * DIM_);
        float s = 0.f;
#pragma unroll
        for (int i = 0; i < 9; i++) s += dot4(q[i], kp[i]);
        float e = __expf(s * scale);
        sum += e;
        const float4* vp = (const float4*)(Vb + (size_t)key * DIM_);
#pragma unroll
        for (int i = 0; i < 9; i++) {
            float4 vv = vp[i];
            acc[i].x += e * vv.x;
            acc[i].y += e * vv.y;
            acc[i].z += e * vv.z;
            acc[i].w += e * vv.w;
        }
    }

    float* p = part + ((size_t)(bh * NQ_ + slot) * NCHUNK_ + chunk) * PSTRIDE_;
#pragma unroll
    for (int i = 0; i < 9; i++) ((float4*)p)[i] = acc[i];
    p[DIM_] = sum;
}

// ---------------------------------------------------------------------------
// K7: combine chunk partials -> attn_out for selected queries.
// ---------------------------------------------------------------------------
__global__ __launch_bounds__(256) void combine_kernel(
    const float* __restrict__ part, const int* __restrict__ qlist,
    float* __restrict__ attn_out)
{
    int idx = blockIdx.x * blockDim.x + threadIdx.x;
    if (idx >= BH_ * NQ_ * DIM_) return;
    int d = idx % DIM_;
    int bhslot = idx / DIM_;
    int bh = bhslot / NQ_, slot = bhslot % NQ_;
    const float* base = part + (size_t)bhslot * NCHUNK_ * PSTRIDE_;
    float a = 0.f, s = 0.f;
#pragma unroll
    for (int c = 0; c < NCHUNK_; c++) {
        a += base[c * PSTRIDE_ + d];
        s += base[c * PSTRIDE_ + DIM_];
    }
    int qidx = qlist[bh * NQ_ + slot];
    int b = bh / H_, h = bh % H_;
    attn_out[((size_t)b * L_ + qidx) * D_ + h * DIM_ + d] = a / s;
}

// ---------------------------------------------------------------------------
// K8: LN1: h1 = LayerNorm(x + attn_out). One wave per row.
// ---------------------------------------------------------------------------
__global__ __launch_bounds__(64) void ln1_kernel(
    const float* __restrict__ x, const float* __restrict__ attn,
    const float* __restrict__ g, const float* __restrict__ bb,
    float* __restrict__ h1)
{
    const int row = blockIdx.x;
    const int lane = threadIdx.x;
    const float* xr = x + (size_t)row * D_;
    const float* ar = attn + (size_t)row * D_;

    float vals[5];
    float s = 0.f;
#pragma unroll
    for (int i = 0; i < 5; i++) {
        int j = lane + i * 64;
        float v = (j < D_) ? (xr[j] + ar[j]) : 0.f;
        vals[i] = v;
        s += v;
    }
#pragma unroll
    for (int off = 32; off; off >>= 1) s += __shfl_xor(s, off);
    float mu = s * (1.0f / D_);

    float vs = 0.f;
#pragma unroll
    for (int i = 0; i < 5; i++) {
        int j = lane + i * 64;
        if (j < D_) { float dd = vals[i] - mu; vs += dd * dd; }
    }
#pragma unroll
    for (int off = 32; off; off >>= 1) vs += __shfl_xor(vs, off);
    float rstd = rsqrtf(vs * (1.0f / D_) + EPS_);

#pragma unroll
    for (int i = 0; i < 5; i++) {
        int j = lane + i * 64;
        if (j < D_) h1[(size_t)row * D_ + j] = (vals[i] - mu) * rstd * g[j] + bb[j];
    }
}

// ---------------------------------------------------------------------------
// K9: FFN layer 1: f1 = gelu(h1 @ W1^T + b1). 8 rows/block, 3 cols/thread
// (3 independent weight streams). grid 250, block 192.
// ---------------------------------------------------------------------------
__global__ __launch_bounds__(192) void ffn1_kernel(
    const float* __restrict__ h1,
    const float* __restrict__ W1, const float* __restrict__ b1,
    float* __restrict__ f1)
{
    constexpr int R = 8;
    __shared__ float hs[R][D_];
    const int base = blockIdx.x * R;
    const int tid = threadIdx.x;

    const float4* hsrc = (const float4*)(h1 + (size_t)base * D_);
    float4* hdst = (float4*)&hs[0][0];
    for (int i = tid; i < R * D_ / 4; i += 192) hdst[i] = hsrc[i];
    __syncthreads();

    const int j0 = tid, j1 = tid + 192, j2 = tid + 384;
    const float4* w0 = (const float4*)(W1 + (size_t)j0 * D_);
    const float4* w1 = (const float4*)(W1 + (size_t)j1 * D_);
    const float4* w2 = (const float4*)(W1 + (size_t)j2 * D_);
    float a0[R], a1[R], a2[R];
    float bb0 = b1[j0], bb1 = b1[j1], bb2 = b1[j2];
#pragma unroll
    for (int r = 0; r < R; r++) { a0[r] = bb0; a1[r] = bb1; a2[r] = bb2; }

    for (int d4 = 0; d4 < D_ / 4; d4++) {
        float4 x0 = w0[d4], x1 = w1[d4], x2 = w2[d4];
#pragma unroll
        for (int r = 0; r < R; r++) {
            float4 hv = *(const float4*)&hs[r][d4 * 4];
            a0[r] += dot4(hv, x0);
            a1[r] += dot4(hv, x1);
            a2[r] += dot4(hv, x2);
        }
    }
#pragma unroll
    for (int r = 0; r < R; r++) {
        size_t rowo = (size_t)(base + r) * DFF_;
        f1[rowo + j0] = gelu_exact(a0[r]);
        f1[rowo + j1] = gelu_exact(a1[r]);
        f1[rowo + j2] = gelu_exact(a2[r]);
    }
}

// ---------------------------------------------------------------------------
// K10: FFN layer 2 + residual + LN2. 8 rows/block. grid 250, block 320
// (288 active in compute; 5 waves for LN).
// ---------------------------------------------------------------------------
__global__ __launch_bounds__(320) void ffn2_ln_kernel(
    const float* __restrict__ f1, const float* __restrict__ h1,
    const float* __restrict__ W2, const float* __restrict__ b2,
    const float* __restrict__ g, const float* __restrict__ bb,
    float* __restrict__ out)
{
    constexpr int R = 8;
    __shared__ float fs[R][DFF_];
    __shared__ float hs[R][D_];
    __shared__ float ys[R][D_];
    const int base = blockIdx.x * R;
    const int tid = threadIdx.x;

    const float4* fsrc = (const float4*)(f1 + (size_t)base * DFF_);
    float4* fdst = (float4*)&fs[0][0];
    for (int i = tid; i < R * DFF_ / 4; i += 320) fdst[i] = fsrc[i];
    const float4* hsrc = (const float4*)(h1 + (size_t)base * D_);
    float4* hdst = (float4*)&hs[0][0];
    for (int i = tid; i < R * D_ / 4; i += 320) hdst[i] = hsrc[i];
    __syncthreads();

    if (tid < D_) {
        const float4* w4 = (const float4*)(W2 + (size_t)tid * DFF_);
        float acc[R];
        float bias = b2[tid];
#pragma unroll
        for (int r = 0; r < R; r++) acc[r] = bias;
        for (int d4 = 0; d4 < DFF_ / 4; d4++) {
            float4 wv = w4[d4];
#pragma unroll
            for (int r = 0; r < R; r++) {
                float4 fv = *(const float4*)&fs[r][d4 * 4];
                acc[r] += dot4(fv, wv);
            }
        }
#pragma unroll
        for (int r = 0; r < R; r++) ys[r][tid] = gelu_exact(acc[r]) + hs[r][tid];
    }
    __syncthreads();

    const int w = tid >> 6;
    const int lane = tid & 63;
    for (int r = w; r < R; r += 5) {
        float s = 0.f, ss = 0.f;
#pragma unroll
        for (int i = 0; i < 5; i++) {
            int j = lane + i * 64;
            if (j < D_) { float y = ys[r][j]; s += y; ss += y * y; }
        }
#pragma unroll
        for (int off = 32; off; off >>= 1) {
            s += __shfl_xor(s, off);
            ss += __shfl_xor(ss, off);
        }
        float mu = s * (1.0f / D_);
        float var = ss * (1.0f / D_) - mu * mu;
        float rstd = rsqrtf(var + EPS_);
        int row = base + r;
#pragma unroll
        for (int i = 0; i < 5; i++) {
            int j = lane + i * 64;
            if (j < D_) out[(size_t)row * D_ + j] = (ys[r][j] - mu) * rstd * g[j] + bb[j];
        }
    }
}

// ---------------------------------------------------------------------------
extern "C" void kernel_launch(void* const* d_in, const int* in_sizes, int n_in,
                              void* d_out, int out_size, void* d_ws, size_t ws_size,
                              hipStream_t stream)
{
    const float* x         = (const float*)d_in[0];
    const int*   index_key = (const int*)  d_in[1];
    const float* Wq = (const float*)d_in[2];
    const float* bq = (const float*)d_in[3];
    const float* Wk = (const float*)d_in[4];
    const float* bk = (const float*)d_in[5];
    const float* Wv = (const float*)d_in[6];
    const float* bv = (const float*)d_in[7];
    const float* W1 = (const float*)d_in[8];
    const float* b1 = (const float*)d_in[9];
    const float* W2 = (const float*)d_in[10];
    const float* b2 = (const float*)d_in[11];
    const float* ln1_g = (const float*)d_in[12];
    const float* ln1_b = (const float*)d_in[13];
    const float* ln2_g = (const float*)d_in[14];
    const float* ln2_b = (const float*)d_in[15];
    float* out = (float*)d_out;

    // workspace carve (floats)
    float* Q        = (float*)d_ws;                      // 576000
    float* K        = Q + (size_t)BH_ * L_ * DIM_;       // 576000
    float* V        = K + (size_t)BH_ * L_ * DIM_;       // 576000
    float* Vmean    = V + (size_t)BH_ * L_ * DIM_;       // 576
    float* measure  = Vmean + BH_ * DIM_;                // 16000
    float* attn_out = measure + BH_ * L_;                // 576000
    float* h1       = attn_out + (size_t)B_ * L_ * D_;   // 576000
    float* part     = h1 + (size_t)B_ * L_ * D_;         // 1280000
    float* f1       = part;                              // aliases part (dead after combine); needs 1152000
    int*   qlist    = (int*)(part + (size_t)BH_ * NQ_ * NCHUNK_ * PSTRIDE_); // 4000
    int*   qcnt     = qlist + BH_ * NQ_;                 // 16

    qkv_kernel<<<250, 320, 0, stream>>>(x, Wq, bq, Wk, bk, Wv, bv, Q, K, V);
    vmean_kernel<<<BH_, 256, 0, stream>>>(V, Vmean);
    measure_kernel<<<4000, 256, 0, stream>>>(Q, K, index_key, measure);
    hipMemsetAsync(qcnt, 0, BH_ * sizeof(int), stream);
    topk_kernel<<<BH_ * 4, 256, 0, stream>>>(measure, qlist, qcnt);
    fill_kernel<<<(B_ * L_ * D_ + 255) / 256, 256, 0, stream>>>(Vmean, attn_out);
    attn_part_kernel<<<BH_ * NCHUNK_, 256, 0, stream>>>(Q, K, V, qlist, part);
    combine_kernel<<<(BH_ * NQ_ * DIM_ + 255) / 256, 256, 0, stream>>>(part, qlist, attn_out);
    ln1_kernel<<<B_ * L_, 64, 0, stream>>>(x, attn_out, ln1_g, ln1_b, h1);
    ffn1_kernel<<<250, 192, 0, stream>>>(h1, W1, b1, f1);
    ffn2_ln_kernel<<<250, 320, 0, stream>>>(f1, h1, W2, b2, ln2_g, ln2_b, out);
}

// Round 4
// 453.110 us; speedup vs baseline: 1.2703x; 1.0826x over previous
//
#include <hip/hip_runtime.h>
#include <hip/hip_bf16.h>
#include <math.h>

// Problem constants
#define B_ 2
#define L_ 1000
#define D_ 288
#define H_ 8
#define DIM_ 36
#define DFF_ 576
#define KS_ 250
#define NQ_ 250
#define BH_ (B_ * H_)
#define EPS_ 1e-5f
#define PSTRIDE_ 40             // partial row: 36 acc + 1 sum, padded to 40

__device__ __forceinline__ float gelu_exact(float x) {
    return 0.5f * x * (1.0f + erff(x * 0.70710678118654752f));
}

__device__ __forceinline__ float dot4(float4 a, float4 b) {
    return a.x * b.x + a.y * b.y + a.z * b.z + a.w * b.w;
}

// ---------------------------------------------------------------------------
// K1: QKV projection. 8 rows/block; thread tid computes column tid of
// Wq, Wk AND Wv (3 independent weight streams -> ILP). grid 250, block 320.
// ---------------------------------------------------------------------------
__global__ __launch_bounds__(320) void qkv_kernel(
    const float* __restrict__ x,
    const float* __restrict__ Wq, const float* __restrict__ bq,
    const float* __restrict__ Wk, const float* __restrict__ bk,
    const float* __restrict__ Wv, const float* __restrict__ bv,
    float* __restrict__ Q, float* __restrict__ K, float* __restrict__ V)
{
    constexpr int R = 8;
    __shared__ float xs[R][D_];
    const int base = blockIdx.x * R;
    const int tid = threadIdx.x;

    const float4* xsrc = (const float4*)(x + (size_t)base * D_);
    float4* xdst = (float4*)&xs[0][0];
    for (int i = tid; i < R * D_ / 4; i += 320) xdst[i] = xsrc[i];
    __syncthreads();

    if (tid < D_) {
        const float4* wq4 = (const float4*)(Wq + (size_t)tid * D_);
        const float4* wk4 = (const float4*)(Wk + (size_t)tid * D_);
        const float4* wv4 = (const float4*)(Wv + (size_t)tid * D_);
        float aq[R], ak[R], av[R];
        float biasq = bq[tid], biask = bk[tid], biasv = bv[tid];
#pragma unroll
        for (int r = 0; r < R; r++) { aq[r] = biasq; ak[r] = biask; av[r] = biasv; }
        for (int d4 = 0; d4 < D_ / 4; d4++) {
            float4 wqv = wq4[d4], wkv = wk4[d4], wvv = wv4[d4];
#pragma unroll
            for (int r = 0; r < R; r++) {
                float4 hv = *(const float4*)&xs[r][d4 * 4];
                aq[r] += dot4(hv, wqv);
                ak[r] += dot4(hv, wkv);
                av[r] += dot4(hv, wvv);
            }
        }
        const int h = tid / DIM_, dd = tid % DIM_;
#pragma unroll
        for (int r = 0; r < R; r++) {
            int row = base + r;
            int b = row / L_, l = row % L_;
            size_t o = ((size_t)(b * H_ + h) * L_ + l) * DIM_ + dd;
            Q[o] = aq[r]; K[o] = ak[r]; V[o] = av[r];
        }
    }
}

// ---------------------------------------------------------------------------
// K2: Vmean[bh, d]. Block per bh.
// ---------------------------------------------------------------------------
__global__ __launch_bounds__(256) void vmean_kernel(
    const float* __restrict__ V, float* __restrict__ Vmean)
{
    const int bh = blockIdx.x;
    const int tid = threadIdx.x;
    __shared__ float red[7][DIM_];
    if (tid < 252) {
        int g = tid / DIM_, d = tid % DIM_;
        const float* base = V + (size_t)bh * L_ * DIM_;
        float s = 0.f;
        for (int l = g; l < L_; l += 7) s += base[l * DIM_ + d];
        red[g][d] = s;
    }
    __syncthreads();
    if (tid < DIM_) {
        float s = 0.f;
#pragma unroll
        for (int g = 0; g < 7; g++) s += red[g][tid];
        Vmean[bh * DIM_ + tid] = s * (1.0f / L_);
    }
}

// ---------------------------------------------------------------------------
// K3: sparsity measure. One wave per (bh, l).
// ---------------------------------------------------------------------------
__global__ __launch_bounds__(256) void measure_kernel(
    const float* __restrict__ Q, const float* __restrict__ K,
    const int* __restrict__ index_key, float* __restrict__ measure)
{
    const int w = threadIdx.x >> 6;
    const int lane = threadIdx.x & 63;
    const int wid = blockIdx.x * 4 + w;      // 0..15999
    const int bh = wid / L_;
    const int l = wid % L_;

    const float4* qp = (const float4*)(Q + ((size_t)bh * L_ + l) * DIM_);
    float4 q[9];
#pragma unroll
    for (int i = 0; i < 9; i++) q[i] = qp[i];

    const int* ik = index_key + l * KS_;
    const float* Kb = K + (size_t)bh * L_ * DIM_;

    float mx = -1e30f, sm = 0.f;
#pragma unroll
    for (int s = lane; s < KS_; s += 64) {
        int kidx = ik[s];
        const float4* k4 = (const float4*)(Kb + (size_t)kidx * DIM_);
        float acc = 0.f;
#pragma unroll
        for (int i = 0; i < 9; i++) acc += dot4(q[i], k4[i]);
        mx = fmaxf(mx, acc);
        sm += acc;
    }
#pragma unroll
    for (int off = 32; off; off >>= 1) {
        mx = fmaxf(mx, __shfl_xor(mx, off));
        sm += __shfl_xor(sm, off);
    }
    if (lane == 0) measure[wid] = mx - sm * (1.0f / (float)L_);
}

// ---------------------------------------------------------------------------
// K4: top-NQ per (b,h) via rank counting; grid 64 (bh x quarter),
// global atomic counter per bh (zeroed via memsetAsync before launch).
// ---------------------------------------------------------------------------
__global__ __launch_bounds__(256) void topk_kernel(
    const float* __restrict__ measure, int* __restrict__ qlist,
    int* __restrict__ qcnt)
{
    const int bh = blockIdx.x >> 2;
    const int quarter = blockIdx.x & 3;
    __shared__ float m[L_];
    for (int i = threadIdx.x; i < L_; i += 256) m[i] = measure[bh * L_ + i];
    __syncthreads();
    const int i = quarter * 250 + threadIdx.x;
    if (threadIdx.x < 250) {
        float mi = m[i];
        int rank = 0;
        for (int j = 0; j < L_; j++) {
            float mj = m[j];
            rank += (mj > mi) || (mj == mi && j < i);
        }
        if (rank < NQ_) {
            int pos = atomicAdd(&qcnt[bh], 1);
            qlist[bh * NQ_ + pos] = i;
        }
    }
}

// ---------------------------------------------------------------------------
// K5: fill attn_out with Vmean broadcast.
// ---------------------------------------------------------------------------
__global__ __launch_bounds__(256) void fill_kernel(
    const float* __restrict__ Vmean, float* __restrict__ attn_out)
{
    int idx = blockIdx.x * blockDim.x + threadIdx.x;
    if (idx >= B_ * L_ * D_) return;
    int d = idx % D_;
    int bl = idx / D_;
    int b = bl / L_;
    int h = d / DIM_, dd = d % DIM_;
    attn_out[idx] = Vmean[(b * H_ + h) * DIM_ + dd];
}

// ---------------------------------------------------------------------------
// K6: attention partials. Block = (bh, key-chunk); thread = selected query.
// Wave-uniform K/V addresses; raw-exp softmax partials are additive.
// grid BH_*nchunk, block 256 (250 active). chunk_len = L_/nchunk.
// ---------------------------------------------------------------------------
__global__ __launch_bounds__(256) void attn_part_kernel(
    const float* __restrict__ Q, const float* __restrict__ K,
    const float* __restrict__ V, const int* __restrict__ qlist,
    float* __restrict__ part, int nchunk, int chunk_len)
{
    const int bh = blockIdx.x / nchunk;
    const int chunk = blockIdx.x % nchunk;
    const int slot = threadIdx.x;
    if (slot >= NQ_) return;

    const int qidx = qlist[bh * NQ_ + slot];
    const float4* qp = (const float4*)(Q + ((size_t)bh * L_ + qidx) * DIM_);
    float4 q[9];
#pragma unroll
    for (int i = 0; i < 9; i++) q[i] = qp[i];

    const float* Kb = K + (size_t)bh * L_ * DIM_;
    const float* Vb = V + (size_t)bh * L_ * DIM_;
    const float scale = (float)(1.0 / 6.0);

    float4 acc[9];
#pragma unroll
    for (int i = 0; i < 9; i++) acc[i] = make_float4(0.f, 0.f, 0.f, 0.f);
    float sum = 0.f;

    const int k0 = chunk * chunk_len;
    for (int j = 0; j < chunk_len; j++) {
        const int key = k0 + j;                       // wave-uniform
        const float4* kp = (const float4*)(Kb + (size_t)key * DIM_);
        float s = 0.f;
#pragma unroll
        for (int i = 0; i < 9; i++) s += dot4(q[i], kp[i]);
        float e = __expf(s * scale);
        sum += e;
        const float4* vp = (const float4*)(Vb + (size_t)key * DIM_);
#pragma unroll
        for (int i = 0; i < 9; i++) {
            float4 vv = vp[i];
            acc[i].x += e * vv.x;
            acc[i].y += e * vv.y;
            acc[i].z += e * vv.z;
            acc[i].w += e * vv.w;
        }
    }

    float* p = part + ((size_t)(bh * NQ_ + slot) * nchunk + chunk) * PSTRIDE_;
#pragma unroll
    for (int i = 0; i < 9; i++) ((float4*)p)[i] = acc[i];
    p[DIM_] = sum;
}

// ---------------------------------------------------------------------------
// K7: combine chunk partials -> attn_out for selected queries.
// ---------------------------------------------------------------------------
__global__ __launch_bounds__(256) void combine_kernel(
    const float* __restrict__ part, const int* __restrict__ qlist,
    float* __restrict__ attn_out, int nchunk)
{
    int idx = blockIdx.x * blockDim.x + threadIdx.x;
    if (idx >= BH_ * NQ_ * DIM_) return;
    int d = idx % DIM_;
    int bhslot = idx / DIM_;
    int bh = bhslot / NQ_, slot = bhslot % NQ_;
    const float* base = part + (size_t)bhslot * nchunk * PSTRIDE_;
    float a = 0.f, s = 0.f;
    for (int c = 0; c < nchunk; c++) {
        a += base[c * PSTRIDE_ + d];
        s += base[c * PSTRIDE_ + DIM_];
    }
    int qidx = qlist[bh * NQ_ + slot];
    int b = bh / H_, h = bh % H_;
    attn_out[((size_t)b * L_ + qidx) * D_ + h * DIM_ + d] = a / s;
}

// ---------------------------------------------------------------------------
// K8: LN1: h1 = LayerNorm(x + attn_out). One wave per row.
// ---------------------------------------------------------------------------
__global__ __launch_bounds__(64) void ln1_kernel(
    const float* __restrict__ x, const float* __restrict__ attn,
    const float* __restrict__ g, const float* __restrict__ bb,
    float* __restrict__ h1)
{
    const int row = blockIdx.x;
    const int lane = threadIdx.x;
    const float* xr = x + (size_t)row * D_;
    const float* ar = attn + (size_t)row * D_;

    float vals[5];
    float s = 0.f;
#pragma unroll
    for (int i = 0; i < 5; i++) {
        int j = lane + i * 64;
        float v = (j < D_) ? (xr[j] + ar[j]) : 0.f;
        vals[i] = v;
        s += v;
    }
#pragma unroll
    for (int off = 32; off; off >>= 1) s += __shfl_xor(s, off);
    float mu = s * (1.0f / D_);

    float vs = 0.f;
#pragma unroll
    for (int i = 0; i < 5; i++) {
        int j = lane + i * 64;
        if (j < D_) { float dd = vals[i] - mu; vs += dd * dd; }
    }
#pragma unroll
    for (int off = 32; off; off >>= 1) vs += __shfl_xor(vs, off);
    float rstd = rsqrtf(vs * (1.0f / D_) + EPS_);

#pragma unroll
    for (int i = 0; i < 5; i++) {
        int j = lane + i * 64;
        if (j < D_) h1[(size_t)row * D_ + j] = (vals[i] - mu) * rstd * g[j] + bb[j];
    }
}

// ---------------------------------------------------------------------------
// K9: FFN layer 1: f1 = gelu(h1 @ W1^T + b1). 8 rows/block, 3 cols/thread.
// grid 250, block 192.
// ---------------------------------------------------------------------------
__global__ __launch_bounds__(192) void ffn1_kernel(
    const float* __restrict__ h1,
    const float* __restrict__ W1, const float* __restrict__ b1,
    float* __restrict__ f1)
{
    constexpr int R = 8;
    __shared__ float hs[R][D_];
    const int base = blockIdx.x * R;
    const int tid = threadIdx.x;

    const float4* hsrc = (const float4*)(h1 + (size_t)base * D_);
    float4* hdst = (float4*)&hs[0][0];
    for (int i = tid; i < R * D_ / 4; i += 192) hdst[i] = hsrc[i];
    __syncthreads();

    const int j0 = tid, j1 = tid + 192, j2 = tid + 384;
    const float4* w0 = (const float4*)(W1 + (size_t)j0 * D_);
    const float4* w1 = (const float4*)(W1 + (size_t)j1 * D_);
    const float4* w2 = (const float4*)(W1 + (size_t)j2 * D_);
    float a0[R], a1[R], a2[R];
    float bb0 = b1[j0], bb1 = b1[j1], bb2 = b1[j2];
#pragma unroll
    for (int r = 0; r < R; r++) { a0[r] = bb0; a1[r] = bb1; a2[r] = bb2; }

    for (int d4 = 0; d4 < D_ / 4; d4++) {
        float4 x0 = w0[d4], x1 = w1[d4], x2 = w2[d4];
#pragma unroll
        for (int r = 0; r < R; r++) {
            float4 hv = *(const float4*)&hs[r][d4 * 4];
            a0[r] += dot4(hv, x0);
            a1[r] += dot4(hv, x1);
            a2[r] += dot4(hv, x2);
        }
    }
#pragma unroll
    for (int r = 0; r < R; r++) {
        size_t rowo = (size_t)(base + r) * DFF_;
        f1[rowo + j0] = gelu_exact(a0[r]);
        f1[rowo + j1] = gelu_exact(a1[r]);
        f1[rowo + j2] = gelu_exact(a2[r]);
    }
}

// ---------------------------------------------------------------------------
// K10: FFN layer 2 + residual + LN2. 8 rows/block. grid 250, block 320.
// ---------------------------------------------------------------------------
__global__ __launch_bounds__(320) void ffn2_ln_kernel(
    const float* __restrict__ f1, const float* __restrict__ h1,
    const float* __restrict__ W2, const float* __restrict__ b2,
    const float* __restrict__ g, const float* __restrict__ bb,
    float* __restrict__ out)
{
    constexpr int R = 8;
    __shared__ float fs[R][DFF_];
    __shared__ float hs[R][D_];
    __shared__ float ys[R][D_];
    const int base = blockIdx.x * R;
    const int tid = threadIdx.x;

    const float4* fsrc = (const float4*)(f1 + (size_t)base * DFF_);
    float4* fdst = (float4*)&fs[0][0];
    for (int i = tid; i < R * DFF_ / 4; i += 320) fdst[i] = fsrc[i];
    const float4* hsrc = (const float4*)(h1 + (size_t)base * D_);
    float4* hdst = (float4*)&hs[0][0];
    for (int i = tid; i < R * D_ / 4; i += 320) hdst[i] = hsrc[i];
    __syncthreads();

    if (tid < D_) {
        const float4* w4 = (const float4*)(W2 + (size_t)tid * DFF_);
        float acc[R];
        float bias = b2[tid];
#pragma unroll
        for (int r = 0; r < R; r++) acc[r] = bias;
        for (int d4 = 0; d4 < DFF_ / 4; d4++) {
            float4 wv = w4[d4];
#pragma unroll
            for (int r = 0; r < R; r++) {
                float4 fv = *(const float4*)&fs[r][d4 * 4];
                acc[r] += dot4(fv, wv);
            }
        }
#pragma unroll
        for (int r = 0; r < R; r++) ys[r][tid] = gelu_exact(acc[r]) + hs[r][tid];
    }
    __syncthreads();

    const int w = tid >> 6;
    const int lane = tid & 63;
    for (int r = w; r < R; r += 5) {
        float s = 0.f, ss = 0.f;
#pragma unroll
        for (int i = 0; i < 5; i++) {
            int j = lane + i * 64;
            if (j < D_) { float y = ys[r][j]; s += y; ss += y * y; }
        }
#pragma unroll
        for (int off = 32; off; off >>= 1) {
            s += __shfl_xor(s, off);
            ss += __shfl_xor(ss, off);
        }
        float mu = s * (1.0f / D_);
        float var = ss * (1.0f / D_) - mu * mu;
        float rstd = rsqrtf(var + EPS_);
        int row = base + r;
#pragma unroll
        for (int i = 0; i < 5; i++) {
            int j = lane + i * 64;
            if (j < D_) out[(size_t)row * D_ + j] = (ys[r][j] - mu) * rstd * g[j] + bb[j];
        }
    }
}

// ---------------------------------------------------------------------------
extern "C" void kernel_launch(void* const* d_in, const int* in_sizes, int n_in,
                              void* d_out, int out_size, void* d_ws, size_t ws_size,
                              hipStream_t stream)
{
    const float* x         = (const float*)d_in[0];
    const int*   index_key = (const int*)  d_in[1];
    const float* Wq = (const float*)d_in[2];
    const float* bq = (const float*)d_in[3];
    const float* Wk = (const float*)d_in[4];
    const float* bk = (const float*)d_in[5];
    const float* Wv = (const float*)d_in[6];
    const float* bv = (const float*)d_in[7];
    const float* W1 = (const float*)d_in[8];
    const float* b1 = (const float*)d_in[9];
    const float* W2 = (const float*)d_in[10];
    const float* b2 = (const float*)d_in[11];
    const float* ln1_g = (const float*)d_in[12];
    const float* ln1_b = (const float*)d_in[13];
    const float* ln2_g = (const float*)d_in[14];
    const float* ln2_b = (const float*)d_in[15];
    float* out = (float*)d_out;

    // workspace carve (floats)
    float* Q        = (float*)d_ws;                      // 576000
    float* K        = Q + 576000;
    float* V        = K + 576000;
    float* Vmean    = V + 576000;                        // 576
    float* measure  = Vmean + 576;                       // 16000
    float* attn_out = measure + 16000;                   // 576000
    float* h1       = attn_out + 576000;                 // 576000
    int*   qlist    = (int*)(h1 + 576000);               // 4000
    int*   qcnt     = qlist + 4000;                      // 16
    float* part     = (float*)(qcnt + 16);               // shared region
    float* f1       = part;                              // f1 needs 1,152,000 (after part is dead)

    // part needs 16*250*nchunk*40 floats. Base offset = 2,900,608 floats.
    const size_t base_floats = 2900608;
    int nchunk = (ws_size >= (base_floats + 4000000) * sizeof(float)) ? 25 : 8;
    int chunk_len = L_ / nchunk;

    qkv_kernel<<<250, 320, 0, stream>>>(x, Wq, bq, Wk, bk, Wv, bv, Q, K, V);
    vmean_kernel<<<BH_, 256, 0, stream>>>(V, Vmean);
    measure_kernel<<<4000, 256, 0, stream>>>(Q, K, index_key, measure);
    hipMemsetAsync(qcnt, 0, BH_ * sizeof(int), stream);
    topk_kernel<<<BH_ * 4, 256, 0, stream>>>(measure, qlist, qcnt);
    fill_kernel<<<(B_ * L_ * D_ + 255) / 256, 256, 0, stream>>>(Vmean, attn_out);
    attn_part_kernel<<<BH_ * nchunk, 256, 0, stream>>>(Q, K, V, qlist, part, nchunk, chunk_len);
    combine_kernel<<<(BH_ * NQ_ * DIM_ + 255) / 256, 256, 0, stream>>>(part, qlist, attn_out, nchunk);
    ln1_kernel<<<B_ * L_, 64, 0, stream>>>(x, attn_out, ln1_g, ln1_b, h1);
    ffn1_kernel<<<250, 192, 0, stream>>>(h1, W1, b1, f1);
    ffn2_ln_kernel<<<250, 320, 0, stream>>>(f1, h1, W2, b2, ln2_g, ln2_b, out);
}

// Round 5
// 428.665 us; speedup vs baseline: 1.3428x; 1.0570x over previous
//
#include <hip/hip_runtime.h>
#include <hip/hip_bf16.h>
#include <math.h>

// Problem constants
#define B_ 2
#define L_ 1000
#define D_ 288
#define H_ 8
#define DIM_ 36
#define DFF_ 576
#define KS_ 250
#define NQ_ 250
#define BH_ (B_ * H_)
#define EPS_ 1e-5f
#define PSTRIDE_ 40             // partial row: 36 acc + 1 sum, padded to 40

__device__ __forceinline__ float gelu_exact(float x) {
    return 0.5f * x * (1.0f + erff(x * 0.70710678118654752f));
}

__device__ __forceinline__ float dot4(float4 a, float4 b) {
    return a.x * b.x + a.y * b.y + a.z * b.z + a.w * b.w;
}

// ---------------------------------------------------------------------------
// K1: QKV projection. 8 rows/block; thread tid computes column tid of
// Wq, Wk AND Wv (3 independent weight streams -> ILP). grid 250, block 320.
// ---------------------------------------------------------------------------
__global__ __launch_bounds__(320) void qkv_kernel(
    const float* __restrict__ x,
    const float* __restrict__ Wq, const float* __restrict__ bq,
    const float* __restrict__ Wk, const float* __restrict__ bk,
    const float* __restrict__ Wv, const float* __restrict__ bv,
    float* __restrict__ Q, float* __restrict__ K, float* __restrict__ V)
{
    constexpr int R = 8;
    __shared__ float xs[R][D_];
    const int base = blockIdx.x * R;
    const int tid = threadIdx.x;

    const float4* xsrc = (const float4*)(x + (size_t)base * D_);
    float4* xdst = (float4*)&xs[0][0];
    for (int i = tid; i < R * D_ / 4; i += 320) xdst[i] = xsrc[i];
    __syncthreads();

    if (tid < D_) {
        const float4* wq4 = (const float4*)(Wq + (size_t)tid * D_);
        const float4* wk4 = (const float4*)(Wk + (size_t)tid * D_);
        const float4* wv4 = (const float4*)(Wv + (size_t)tid * D_);
        float aq[R], ak[R], av[R];
        float biasq = bq[tid], biask = bk[tid], biasv = bv[tid];
#pragma unroll
        for (int r = 0; r < R; r++) { aq[r] = biasq; ak[r] = biask; av[r] = biasv; }
        for (int d4 = 0; d4 < D_ / 4; d4++) {
            float4 wqv = wq4[d4], wkv = wk4[d4], wvv = wv4[d4];
#pragma unroll
            for (int r = 0; r < R; r++) {
                float4 hv = *(const float4*)&xs[r][d4 * 4];
                aq[r] += dot4(hv, wqv);
                ak[r] += dot4(hv, wkv);
                av[r] += dot4(hv, wvv);
            }
        }
        const int h = tid / DIM_, dd = tid % DIM_;
#pragma unroll
        for (int r = 0; r < R; r++) {
            int row = base + r;
            int b = row / L_, l = row % L_;
            size_t o = ((size_t)(b * H_ + h) * L_ + l) * DIM_ + dd;
            Q[o] = aq[r]; K[o] = ak[r]; V[o] = av[r];
        }
    }
}

// ---------------------------------------------------------------------------
// K2: Vmean[bh, d]. Block per bh.
// ---------------------------------------------------------------------------
__global__ __launch_bounds__(256) void vmean_kernel(
    const float* __restrict__ V, float* __restrict__ Vmean)
{
    const int bh = blockIdx.x;
    const int tid = threadIdx.x;
    __shared__ float red[7][DIM_];
    if (tid < 252) {
        int g = tid / DIM_, d = tid % DIM_;
        const float* base = V + (size_t)bh * L_ * DIM_;
        float s = 0.f;
        for (int l = g; l < L_; l += 7) s += base[l * DIM_ + d];
        red[g][d] = s;
    }
    __syncthreads();
    if (tid < DIM_) {
        float s = 0.f;
#pragma unroll
        for (int g = 0; g < 7; g++) s += red[g][tid];
        Vmean[bh * DIM_ + tid] = s * (1.0f / L_);
    }
}

// ---------------------------------------------------------------------------
// K3a: dense scores S[bh][lq][lk] = Q . K (unscaled). ffn1-style: 8 queries
// staged in LDS (broadcast reads), thread = key, 4 keys/thread.
// grid 16*125 = 2000, block 256.
// ---------------------------------------------------------------------------
__global__ __launch_bounds__(256) void score_kernel(
    const float* __restrict__ Q, const float* __restrict__ K,
    float* __restrict__ S)
{
    constexpr int R = 8;
    const int bh = blockIdx.x / 125;
    const int qt = blockIdx.x % 125;
    const int tid = threadIdx.x;
    __shared__ float qs[R][DIM_];

    if (tid < R * DIM_ / 4)
        ((float4*)&qs[0][0])[tid] =
            ((const float4*)(Q + ((size_t)bh * L_ + qt * R) * DIM_))[tid];
    __syncthreads();

    const float* Kb = K + (size_t)bh * L_ * DIM_;
    float* Sb = S + ((size_t)bh * L_ + qt * R) * L_;

#pragma unroll
    for (int i = 0; i < 4; i++) {
        int k = i * 256 + tid;
        if (k < L_) {
            const float4* kp = (const float4*)(Kb + (size_t)k * DIM_);
            float acc[R];
#pragma unroll
            for (int r = 0; r < R; r++) acc[r] = 0.f;
#pragma unroll
            for (int d4 = 0; d4 < DIM_ / 4; d4++) {
                float4 kv = kp[d4];
#pragma unroll
                for (int r = 0; r < R; r++)
                    acc[r] += dot4(*(const float4*)&qs[r][d4 * 4], kv);
            }
#pragma unroll
            for (int r = 0; r < R; r++) Sb[(size_t)r * L_ + k] = acc[r];
        }
    }
}

// ---------------------------------------------------------------------------
// K3b: measure from dense S: 4B gathers instead of 144B row gathers.
// One wave per (bh,l). grid 4000, block 256.
// ---------------------------------------------------------------------------
__global__ __launch_bounds__(256) void measure2_kernel(
    const float* __restrict__ S, const int* __restrict__ index_key,
    float* __restrict__ measure)
{
    const int w = threadIdx.x >> 6;
    const int lane = threadIdx.x & 63;
    const int wid = blockIdx.x * 4 + w;      // 0..15999
    const int bh = wid / L_;
    const int l = wid % L_;

    const float* Srow = S + ((size_t)bh * L_ + l) * L_;
    const int* ik = index_key + l * KS_;

    float mx = -1e30f, sm = 0.f;
#pragma unroll
    for (int s = lane; s < KS_; s += 64) {
        float v = Srow[ik[s]];
        mx = fmaxf(mx, v);
        sm += v;
    }
#pragma unroll
    for (int off = 32; off; off >>= 1) {
        mx = fmaxf(mx, __shfl_xor(mx, off));
        sm += __shfl_xor(sm, off);
    }
    if (lane == 0) measure[wid] = mx - sm * (1.0f / (float)L_);
}

// ---------------------------------------------------------------------------
// K3-fallback: gather-based measure (R4 path, used if workspace too small).
// ---------------------------------------------------------------------------
__global__ __launch_bounds__(256) void measure_kernel(
    const float* __restrict__ Q, const float* __restrict__ K,
    const int* __restrict__ index_key, float* __restrict__ measure)
{
    const int w = threadIdx.x >> 6;
    const int lane = threadIdx.x & 63;
    const int wid = blockIdx.x * 4 + w;
    const int bh = wid / L_;
    const int l = wid % L_;

    const float4* qp = (const float4*)(Q + ((size_t)bh * L_ + l) * DIM_);
    float4 q[9];
#pragma unroll
    for (int i = 0; i < 9; i++) q[i] = qp[i];

    const int* ik = index_key + l * KS_;
    const float* Kb = K + (size_t)bh * L_ * DIM_;

    float mx = -1e30f, sm = 0.f;
#pragma unroll
    for (int s = lane; s < KS_; s += 64) {
        int kidx = ik[s];
        const float4* k4 = (const float4*)(Kb + (size_t)kidx * DIM_);
        float acc = 0.f;
#pragma unroll
        for (int i = 0; i < 9; i++) acc += dot4(q[i], k4[i]);
        mx = fmaxf(mx, acc);
        sm += acc;
    }
#pragma unroll
    for (int off = 32; off; off >>= 1) {
        mx = fmaxf(mx, __shfl_xor(mx, off));
        sm += __shfl_xor(sm, off);
    }
    if (lane == 0) measure[wid] = mx - sm * (1.0f / (float)L_);
}

// ---------------------------------------------------------------------------
// K4: top-NQ per (b,h) via rank counting; grid 64.
// ---------------------------------------------------------------------------
__global__ __launch_bounds__(256) void topk_kernel(
    const float* __restrict__ measure, int* __restrict__ qlist,
    int* __restrict__ qcnt)
{
    const int bh = blockIdx.x >> 2;
    const int quarter = blockIdx.x & 3;
    __shared__ float m[L_];
    for (int i = threadIdx.x; i < L_; i += 256) m[i] = measure[bh * L_ + i];
    __syncthreads();
    const int i = quarter * 250 + threadIdx.x;
    if (threadIdx.x < 250) {
        float mi = m[i];
        int rank = 0;
        for (int j = 0; j < L_; j++) {
            float mj = m[j];
            rank += (mj > mi) || (mj == mi && j < i);
        }
        if (rank < NQ_) {
            int pos = atomicAdd(&qcnt[bh], 1);
            qlist[bh * NQ_ + pos] = i;
        }
    }
}

// ---------------------------------------------------------------------------
// K5: fill attn_out with Vmean broadcast.
// ---------------------------------------------------------------------------
__global__ __launch_bounds__(256) void fill_kernel(
    const float* __restrict__ Vmean, float* __restrict__ attn_out)
{
    int idx = blockIdx.x * blockDim.x + threadIdx.x;
    if (idx >= B_ * L_ * D_) return;
    int d = idx % D_;
    int bl = idx / D_;
    int b = bl / L_;
    int h = d / DIM_, dd = d % DIM_;
    attn_out[idx] = Vmean[(b * H_ + h) * DIM_ + dd];
}

// ---------------------------------------------------------------------------
// K6a: attention partials from dense S. Thread = selected query; per key:
// one 4B gather from S + wave-uniform V broadcast. grid BH_*nchunk, block 256.
// ---------------------------------------------------------------------------
__global__ __launch_bounds__(256) void attn_part2_kernel(
    const float* __restrict__ S, const float* __restrict__ V,
    const int* __restrict__ qlist, float* __restrict__ part,
    int nchunk, int chunk_len)
{
    const int bh = blockIdx.x / nchunk;
    const int chunk = blockIdx.x % nchunk;
    const int slot = threadIdx.x;
    if (slot >= NQ_) return;

    const int qidx = qlist[bh * NQ_ + slot];
    const float* Srow = S + ((size_t)bh * L_ + qidx) * L_;
    const float* Vb = V + (size_t)bh * L_ * DIM_;
    const float scale = (float)(1.0 / 6.0);

    float4 acc[9];
#pragma unroll
    for (int i = 0; i < 9; i++) acc[i] = make_float4(0.f, 0.f, 0.f, 0.f);
    float sum = 0.f;

    const int k0 = chunk * chunk_len;
    for (int j = 0; j < chunk_len; j++) {
        const int key = k0 + j;                       // wave-uniform
        float e = __expf(Srow[key] * scale);
        sum += e;
        const float4* vp = (const float4*)(Vb + (size_t)key * DIM_);
#pragma unroll
        for (int i = 0; i < 9; i++) {
            float4 vv = vp[i];
            acc[i].x += e * vv.x;
            acc[i].y += e * vv.y;
            acc[i].z += e * vv.z;
            acc[i].w += e * vv.w;
        }
    }

    float* p = part + ((size_t)(bh * NQ_ + slot) * nchunk + chunk) * PSTRIDE_;
#pragma unroll
    for (int i = 0; i < 9; i++) ((float4*)p)[i] = acc[i];
    p[DIM_] = sum;
}

// ---------------------------------------------------------------------------
// K6-fallback: partials with K dots (R4 path).
// ---------------------------------------------------------------------------
__global__ __launch_bounds__(256) void attn_part_kernel(
    const float* __restrict__ Q, const float* __restrict__ K,
    const float* __restrict__ V, const int* __restrict__ qlist,
    float* __restrict__ part, int nchunk, int chunk_len)
{
    const int bh = blockIdx.x / nchunk;
    const int chunk = blockIdx.x % nchunk;
    const int slot = threadIdx.x;
    if (slot >= NQ_) return;

    const int qidx = qlist[bh * NQ_ + slot];
    const float4* qp = (const float4*)(Q + ((size_t)bh * L_ + qidx) * DIM_);
    float4 q[9];
#pragma unroll
    for (int i = 0; i < 9; i++) q[i] = qp[i];

    const float* Kb = K + (size_t)bh * L_ * DIM_;
    const float* Vb = V + (size_t)bh * L_ * DIM_;
    const float scale = (float)(1.0 / 6.0);

    float4 acc[9];
#pragma unroll
    for (int i = 0; i < 9; i++) acc[i] = make_float4(0.f, 0.f, 0.f, 0.f);
    float sum = 0.f;

    const int k0 = chunk * chunk_len;
    for (int j = 0; j < chunk_len; j++) {
        const int key = k0 + j;
        const float4* kp = (const float4*)(Kb + (size_t)key * DIM_);
        float s = 0.f;
#pragma unroll
        for (int i = 0; i < 9; i++) s += dot4(q[i], kp[i]);
        float e = __expf(s * scale);
        sum += e;
        const float4* vp = (const float4*)(Vb + (size_t)key * DIM_);
#pragma unroll
        for (int i = 0; i < 9; i++) {
            float4 vv = vp[i];
            acc[i].x += e * vv.x;
            acc[i].y += e * vv.y;
            acc[i].z += e * vv.z;
            acc[i].w += e * vv.w;
        }
    }

    float* p = part + ((size_t)(bh * NQ_ + slot) * nchunk + chunk) * PSTRIDE_;
#pragma unroll
    for (int i = 0; i < 9; i++) ((float4*)p)[i] = acc[i];
    p[DIM_] = sum;
}

// ---------------------------------------------------------------------------
// K7: combine chunk partials -> attn_out for selected queries.
// ---------------------------------------------------------------------------
__global__ __launch_bounds__(256) void combine_kernel(
    const float* __restrict__ part, const int* __restrict__ qlist,
    float* __restrict__ attn_out, int nchunk)
{
    int idx = blockIdx.x * blockDim.x + threadIdx.x;
    if (idx >= BH_ * NQ_ * DIM_) return;
    int d = idx % DIM_;
    int bhslot = idx / DIM_;
    int bh = bhslot / NQ_, slot = bhslot % NQ_;
    const float* base = part + (size_t)bhslot * nchunk * PSTRIDE_;
    float a = 0.f, s = 0.f;
    for (int c = 0; c < nchunk; c++) {
        a += base[c * PSTRIDE_ + d];
        s += base[c * PSTRIDE_ + DIM_];
    }
    int qidx = qlist[bh * NQ_ + slot];
    int b = bh / H_, h = bh % H_;
    attn_out[((size_t)b * L_ + qidx) * D_ + h * DIM_ + d] = a / s;
}

// ---------------------------------------------------------------------------
// K8: LN1: h1 = LayerNorm(x + attn_out). One wave per row.
// ---------------------------------------------------------------------------
__global__ __launch_bounds__(64) void ln1_kernel(
    const float* __restrict__ x, const float* __restrict__ attn,
    const float* __restrict__ g, const float* __restrict__ bb,
    float* __restrict__ h1)
{
    const int row = blockIdx.x;
    const int lane = threadIdx.x;
    const float* xr = x + (size_t)row * D_;
    const float* ar = attn + (size_t)row * D_;

    float vals[5];
    float s = 0.f;
#pragma unroll
    for (int i = 0; i < 5; i++) {
        int j = lane + i * 64;
        float v = (j < D_) ? (xr[j] + ar[j]) : 0.f;
        vals[i] = v;
        s += v;
    }
#pragma unroll
    for (int off = 32; off; off >>= 1) s += __shfl_xor(s, off);
    float mu = s * (1.0f / D_);

    float vs = 0.f;
#pragma unroll
    for (int i = 0; i < 5; i++) {
        int j = lane + i * 64;
        if (j < D_) { float dd = vals[i] - mu; vs += dd * dd; }
    }
#pragma unroll
    for (int off = 32; off; off >>= 1) vs += __shfl_xor(vs, off);
    float rstd = rsqrtf(vs * (1.0f / D_) + EPS_);

#pragma unroll
    for (int i = 0; i < 5; i++) {
        int j = lane + i * 64;
        if (j < D_) h1[(size_t)row * D_ + j] = (vals[i] - mu) * rstd * g[j] + bb[j];
    }
}

// ---------------------------------------------------------------------------
// K9: FFN layer 1. 8 rows/block, 3 cols/thread. grid 250, block 192.
// ---------------------------------------------------------------------------
__global__ __launch_bounds__(192) void ffn1_kernel(
    const float* __restrict__ h1,
    const float* __restrict__ W1, const float* __restrict__ b1,
    float* __restrict__ f1)
{
    constexpr int R = 8;
    __shared__ float hs[R][D_];
    const int base = blockIdx.x * R;
    const int tid = threadIdx.x;

    const float4* hsrc = (const float4*)(h1 + (size_t)base * D_);
    float4* hdst = (float4*)&hs[0][0];
    for (int i = tid; i < R * D_ / 4; i += 192) hdst[i] = hsrc[i];
    __syncthreads();

    const int j0 = tid, j1 = tid + 192, j2 = tid + 384;
    const float4* w0 = (const float4*)(W1 + (size_t)j0 * D_);
    const float4* w1 = (const float4*)(W1 + (size_t)j1 * D_);
    const float4* w2 = (const float4*)(W1 + (size_t)j2 * D_);
    float a0[R], a1[R], a2[R];
    float bb0 = b1[j0], bb1 = b1[j1], bb2 = b1[j2];
#pragma unroll
    for (int r = 0; r < R; r++) { a0[r] = bb0; a1[r] = bb1; a2[r] = bb2; }

    for (int d4 = 0; d4 < D_ / 4; d4++) {
        float4 x0 = w0[d4], x1 = w1[d4], x2 = w2[d4];
#pragma unroll
        for (int r = 0; r < R; r++) {
            float4 hv = *(const float4*)&hs[r][d4 * 4];
            a0[r] += dot4(hv, x0);
            a1[r] += dot4(hv, x1);
            a2[r] += dot4(hv, x2);
        }
    }
#pragma unroll
    for (int r = 0; r < R; r++) {
        size_t rowo = (size_t)(base + r) * DFF_;
        f1[rowo + j0] = gelu_exact(a0[r]);
        f1[rowo + j1] = gelu_exact(a1[r]);
        f1[rowo + j2] = gelu_exact(a2[r]);
    }
}

// ---------------------------------------------------------------------------
// K10: FFN layer 2 + residual + LN2. 8 rows/block. grid 250, block 320.
// ---------------------------------------------------------------------------
__global__ __launch_bounds__(320) void ffn2_ln_kernel(
    const float* __restrict__ f1, const float* __restrict__ h1,
    const float* __restrict__ W2, const float* __restrict__ b2,
    const float* __restrict__ g, const float* __restrict__ bb,
    float* __restrict__ out)
{
    constexpr int R = 8;
    __shared__ float fs[R][DFF_];
    __shared__ float hs[R][D_];
    __shared__ float ys[R][D_];
    const int base = blockIdx.x * R;
    const int tid = threadIdx.x;

    const float4* fsrc = (const float4*)(f1 + (size_t)base * DFF_);
    float4* fdst = (float4*)&fs[0][0];
    for (int i = tid; i < R * DFF_ / 4; i += 320) fdst[i] = fsrc[i];
    const float4* hsrc = (const float4*)(h1 + (size_t)base * D_);
    float4* hdst = (float4*)&hs[0][0];
    for (int i = tid; i < R * D_ / 4; i += 320) hdst[i] = hsrc[i];
    __syncthreads();

    if (tid < D_) {
        const float4* w4 = (const float4*)(W2 + (size_t)tid * DFF_);
        float acc[R];
        float bias = b2[tid];
#pragma unroll
        for (int r = 0; r < R; r++) acc[r] = bias;
        for (int d4 = 0; d4 < DFF_ / 4; d4++) {
            float4 wv = w4[d4];
#pragma unroll
            for (int r = 0; r < R; r++) {
                float4 fv = *(const float4*)&fs[r][d4 * 4];
                acc[r] += dot4(fv, wv);
            }
        }
#pragma unroll
        for (int r = 0; r < R; r++) ys[r][tid] = gelu_exact(acc[r]) + hs[r][tid];
    }
    __syncthreads();

    const int w = tid >> 6;
    const int lane = tid & 63;
    for (int r = w; r < R; r += 5) {
        float s = 0.f, ss = 0.f;
#pragma unroll
        for (int i = 0; i < 5; i++) {
            int j = lane + i * 64;
            if (j < D_) { float y = ys[r][j]; s += y; ss += y * y; }
        }
#pragma unroll
        for (int off = 32; off; off >>= 1) {
            s += __shfl_xor(s, off);
            ss += __shfl_xor(ss, off);
        }
        float mu = s * (1.0f / D_);
        float var = ss * (1.0f / D_) - mu * mu;
        float rstd = rsqrtf(var + EPS_);
        int row = base + r;
#pragma unroll
        for (int i = 0; i < 5; i++) {
            int j = lane + i * 64;
            if (j < D_) out[(size_t)row * D_ + j] = (ys[r][j] - mu) * rstd * g[j] + bb[j];
        }
    }
}

// ---------------------------------------------------------------------------
extern "C" void kernel_launch(void* const* d_in, const int* in_sizes, int n_in,
                              void* d_out, int out_size, void* d_ws, size_t ws_size,
                              hipStream_t stream)
{
    const float* x         = (const float*)d_in[0];
    const int*   index_key = (const int*)  d_in[1];
    const float* Wq = (const float*)d_in[2];
    const float* bq = (const float*)d_in[3];
    const float* Wk = (const float*)d_in[4];
    const float* bk = (const float*)d_in[5];
    const float* Wv = (const float*)d_in[6];
    const float* bv = (const float*)d_in[7];
    const float* W1 = (const float*)d_in[8];
    const float* b1 = (const float*)d_in[9];
    const float* W2 = (const float*)d_in[10];
    const float* b2 = (const float*)d_in[11];
    const float* ln1_g = (const float*)d_in[12];
    const float* ln1_b = (const float*)d_in[13];
    const float* ln2_g = (const float*)d_in[14];
    const float* ln2_b = (const float*)d_in[15];
    float* out = (float*)d_out;

    // workspace carve (floats) — identical to R4 layout, S appended at end
    float* Q        = (float*)d_ws;                      // 576000
    float* K        = Q + 576000;
    float* V        = K + 576000;
    float* Vmean    = V + 576000;                        // 576
    float* measure  = Vmean + 576;                       // 16000
    float* attn_out = measure + 16000;                   // 576000
    float* h1       = attn_out + 576000;                 // 576000
    int*   qlist    = (int*)(h1 + 576000);               // 4000
    int*   qcnt     = qlist + 4000;                      // 16
    float* part     = (float*)(qcnt + 16);               // up to 4,000,000 (nchunk 25)
    float* f1       = part;                              // f1 (1,152,000) aliases dead part
    float* S        = part + 4000000;                    // 16,000,000 floats (64 MB)

    const size_t part25_end  = 2900592ull + 4000000ull;            //  6,900,592 floats
    const size_t s_end       = part25_end + 16000000ull;           // 22,900,592 floats
    const bool   use_S       = ws_size >= s_end * sizeof(float);
    const bool   big_part    = ws_size >= part25_end * sizeof(float);
    const int    nchunk      = (use_S || big_part) ? 25 : 8;
    const int    chunk_len   = L_ / nchunk;

    qkv_kernel<<<250, 320, 0, stream>>>(x, Wq, bq, Wk, bk, Wv, bv, Q, K, V);
    vmean_kernel<<<BH_, 256, 0, stream>>>(V, Vmean);
    if (use_S) {
        score_kernel<<<BH_ * 125, 256, 0, stream>>>(Q, K, S);
        measure2_kernel<<<4000, 256, 0, stream>>>(S, index_key, measure);
    } else {
        measure_kernel<<<4000, 256, 0, stream>>>(Q, K, index_key, measure);
    }
    hipMemsetAsync(qcnt, 0, BH_ * sizeof(int), stream);
    topk_kernel<<<BH_ * 4, 256, 0, stream>>>(measure, qlist, qcnt);
    fill_kernel<<<(B_ * L_ * D_ + 255) / 256, 256, 0, stream>>>(Vmean, attn_out);
    if (use_S) {
        attn_part2_kernel<<<BH_ * nchunk, 256, 0, stream>>>(S, V, qlist, part, nchunk, chunk_len);
    } else {
        attn_part_kernel<<<BH_ * nchunk, 256, 0, stream>>>(Q, K, V, qlist, part, nchunk, chunk_len);
    }
    combine_kernel<<<(BH_ * NQ_ * DIM_ + 255) / 256, 256, 0, stream>>>(part, qlist, attn_out, nchunk);
    ln1_kernel<<<B_ * L_, 64, 0, stream>>>(x, attn_out, ln1_g, ln1_b, h1);
    ffn1_kernel<<<250, 192, 0, stream>>>(h1, W1, b1, f1);
    ffn2_ln_kernel<<<250, 320, 0, stream>>>(f1, h1, W2, b2, ln2_g, ln2_b, out);
}